// Round 2
// baseline (591.560 us; speedup 1.0000x reference)
//
#include <hip/hip_runtime.h>
#include <cstdint>
#include <cstddef>

#define NUM_REL 20000
#define NUM_EDGES 640000
#define DIM_IN 128
#define DIM_OUT 256
#define NUM_HEAD 8
#define DIM_HID 32
#define NUM_BIN 10
#define NCOLS 768  // P row: [0,256)=ZH (W1*emb), [256,512)=ZT (W2*emb + attn_b), [512,768)=MSG (Wa*emb + aggr_b)

// ---------------------------------------------------------------------------
// Fused GEMM: P[r, :] = [emb@W1^T | emb@W2^T + attn_b | emb@Wa^T + aggr_b]
// BM=BN=128, BK=32, 256 threads, 8x8 per thread (split 4+4).
// ---------------------------------------------------------------------------
__global__ __launch_bounds__(256) void gemm_kernel(
    const float* __restrict__ emb, const float* __restrict__ attn_w,
    const float* __restrict__ attn_b, const float* __restrict__ aggr_w,
    const float* __restrict__ aggr_b, float* __restrict__ P) {
  __shared__ float As[32][132];  // [k][m], stride 132 to break write conflicts
  __shared__ float Bs[32][132];  // [k][n]
  const int tid = threadIdx.x;
  const int m0 = blockIdx.x * 128;
  const int n0 = blockIdx.y * 128;
  const int reg = n0 >> 8;  // 0: W1 (attn_w k 0..127), 1: W2 (attn_w k 128..255), 2: Wa
  const int ty = tid >> 4, tx = tid & 15;
  float acc[2][2][4][4] = {};

  for (int kk = 0; kk < 128; kk += 32) {
    #pragma unroll
    for (int j = 0; j < 4; ++j) {
      int c = tid + j * 256;       // 0..1023 float4 chunks (128 rows x 8 k-chunks)
      int rown = c >> 3, kc = c & 7;
      int gm = m0 + rown;
      float4 av = make_float4(0.f, 0.f, 0.f, 0.f);
      if (gm < NUM_REL) av = *(const float4*)(emb + (size_t)gm * DIM_IN + kk + kc * 4);
      As[kc * 4 + 0][rown] = av.x; As[kc * 4 + 1][rown] = av.y;
      As[kc * 4 + 2][rown] = av.z; As[kc * 4 + 3][rown] = av.w;
      int o = n0 + rown;
      float4 bv;
      if (reg == 0)      bv = *(const float4*)(attn_w + (size_t)o * 256 + kk + kc * 4);
      else if (reg == 1) bv = *(const float4*)(attn_w + (size_t)(o - 256) * 256 + 128 + kk + kc * 4);
      else               bv = *(const float4*)(aggr_w + (size_t)(o - 512) * 128 + kk + kc * 4);
      Bs[kc * 4 + 0][rown] = bv.x; Bs[kc * 4 + 1][rown] = bv.y;
      Bs[kc * 4 + 2][rown] = bv.z; Bs[kc * 4 + 3][rown] = bv.w;
    }
    __syncthreads();
    #pragma unroll
    for (int k = 0; k < 32; ++k) {
      float4 a0 = *(const float4*)&As[k][ty * 4];
      float4 a1 = *(const float4*)&As[k][64 + ty * 4];
      float4 b0 = *(const float4*)&Bs[k][tx * 4];
      float4 b1 = *(const float4*)&Bs[k][64 + tx * 4];
      float am[2][4] = {{a0.x, a0.y, a0.z, a0.w}, {a1.x, a1.y, a1.z, a1.w}};
      float bn[2][4] = {{b0.x, b0.y, b0.z, b0.w}, {b1.x, b1.y, b1.z, b1.w}};
      #pragma unroll
      for (int im = 0; im < 2; ++im)
        #pragma unroll
        for (int in_ = 0; in_ < 2; ++in_)
          #pragma unroll
          for (int i = 0; i < 4; ++i)
            #pragma unroll
            for (int jj = 0; jj < 4; ++jj)
              acc[im][in_][i][jj] += am[im][i] * bn[in_][jj];
    }
    __syncthreads();
  }

  float bias[2][4];
  #pragma unroll
  for (int in_ = 0; in_ < 2; ++in_) {
    #pragma unroll
    for (int jj = 0; jj < 4; ++jj) {
      int gn = n0 + in_ * 64 + tx * 4 + jj;
      float b = 0.f;
      if (gn >= 512)      b = aggr_b[gn - 512];
      else if (gn >= 256) b = attn_b[gn - 256];
      bias[in_][jj] = b;
    }
  }
  #pragma unroll
  for (int im = 0; im < 2; ++im) {
    #pragma unroll
    for (int i = 0; i < 4; ++i) {
      int gm = m0 + im * 64 + ty * 4 + i;
      if (gm >= NUM_REL) continue;
      #pragma unroll
      for (int in_ = 0; in_ < 2; ++in_) {
        int gn = n0 + in_ * 64 + tx * 4;
        float4 v;
        v.x = acc[im][in_][i][0] + bias[in_][0];
        v.y = acc[im][in_][i][1] + bias[in_][1];
        v.z = acc[im][in_][i][2] + bias[in_][2];
        v.w = acc[im][in_][i][3] + bias[in_][3];
        *(float4*)(P + (size_t)gm * NCOLS + gn) = v;
      }
    }
  }
}

// ---------------------------------------------------------------------------
// Per-edge attention logits: raw[e,h] = dot(leakyrelu(ZH[head]+ZT[tail]), vec[h]) + bin[b,h]
// One 64-lane wave per edge; lane l owns components 4l..4l+3 (head h = l>>3).
// Also histograms edges per head relation.
// ---------------------------------------------------------------------------
__global__ __launch_bounds__(256) void edge_raw_kernel(
    const float* __restrict__ P, const int* __restrict__ trip,
    const float* __restrict__ attn_bin, const float* __restrict__ attn_vec,
    float* __restrict__ raw, int* __restrict__ count) {
  const int lane = threadIdx.x & 63;
  const int wib = threadIdx.x >> 6;
  const int gw = blockIdx.x * 4 + wib;
  const int nw = gridDim.x * 4;
  const float4 vv = *(const float4*)(attn_vec + lane * 4);  // uniform per lane
  for (int e = gw; e < NUM_EDGES; e += nw) {
    int hd = trip[e * 3 + 0];
    int tl = trip[e * 3 + 1];
    int bn = trip[e * 3 + 2];
    float4 zh = *(const float4*)(P + (size_t)hd * NCOLS + lane * 4);
    float4 zt = *(const float4*)(P + (size_t)tl * NCOLS + 256 + lane * 4);
    float zx = zh.x + zt.x, zy = zh.y + zt.y, zz = zh.z + zt.z, zw = zh.w + zt.w;
    zx = zx > 0.f ? zx : 0.2f * zx;
    zy = zy > 0.f ? zy : 0.2f * zy;
    zz = zz > 0.f ? zz : 0.2f * zz;
    zw = zw > 0.f ? zw : 0.2f * zw;
    float p = zx * vv.x + zy * vv.y + zz * vv.z + zw * vv.w;
    p += __shfl_xor(p, 1);
    p += __shfl_xor(p, 2);
    p += __shfl_xor(p, 4);  // lanes 8h hold sum over head h's 32 components
    if ((lane & 7) == 0) {
      int h = lane >> 3;
      raw[(size_t)e * 8 + h] = p + attn_bin[bn * 8 + h];
    }
    if (lane == 0) atomicAdd(&count[hd], 1);
  }
}

// ---------------------------------------------------------------------------
// Exclusive scan of per-relation counts -> CSR offsets (+ cursor copy).
// ---------------------------------------------------------------------------
__global__ __launch_bounds__(1024) void scan_kernel(
    const int* __restrict__ count, int* __restrict__ offs, int* __restrict__ cursor) {
  __shared__ int s[1024];
  const int t = threadIdx.x;
  const int base = t * 20;
  int loc[20];
  int sum = 0;
  #pragma unroll
  for (int i = 0; i < 20; ++i) {
    int idx = base + i;
    int v = (idx < NUM_REL) ? count[idx] : 0;
    loc[i] = sum;
    sum += v;
  }
  s[t] = sum;
  __syncthreads();
  for (int off = 1; off < 1024; off <<= 1) {
    int v = 0;
    if (t >= off) v = s[t - off];
    __syncthreads();
    if (t >= off) s[t] += v;
    __syncthreads();
  }
  int prev = (t > 0) ? s[t - 1] : 0;
  #pragma unroll
  for (int i = 0; i < 20; ++i) {
    int idx = base + i;
    if (idx < NUM_REL) {
      int o = prev + loc[i];
      offs[idx] = o;
      cursor[idx] = o;
    }
  }
  if (t == 1023) offs[NUM_REL] = s[1023];
}

// ---------------------------------------------------------------------------
// Bucket fill: elist grouped by head relation.
// ---------------------------------------------------------------------------
__global__ __launch_bounds__(256) void fill_kernel(
    const int* __restrict__ trip, int* __restrict__ cursor, int* __restrict__ elist) {
  int e = blockIdx.x * 256 + threadIdx.x;
  if (e < NUM_EDGES) {
    int r = trip[e * 3];
    int pos = atomicAdd(&cursor[r], 1);
    elist[pos] = e;
  }
}

// ---------------------------------------------------------------------------
// Per-relation: segment max, segment sum(exp), weighted aggregation of MSG rows.
// Block = 256 threads = one relation.
// ---------------------------------------------------------------------------
__global__ __launch_bounds__(256) void aggregate_kernel(
    const float* __restrict__ P, const int* __restrict__ trip,
    const float* __restrict__ raw, const int* __restrict__ offs,
    const int* __restrict__ elist, float* __restrict__ out) {
  const int r = blockIdx.x;
  const int tid = threadIdx.x;
  const int beg = offs[r];
  const int n = offs[r + 1] - beg;
  if (n == 0) {
    out[(size_t)r * 256 + tid] = 0.f;
    return;
  }
  __shared__ float red[32][8];
  __shared__ float amaxS[8], invS[8];
  const int s_ = tid >> 3, h = tid & 7;

  // segment max
  float mx = -3.4e38f;
  for (int i = s_; i < n; i += 32) {
    int e = elist[beg + i];
    mx = fmaxf(mx, raw[(size_t)e * 8 + h]);
  }
  red[s_][h] = mx;
  __syncthreads();
  #pragma unroll
  for (int st = 16; st >= 1; st >>= 1) {
    if (s_ < st) red[s_][h] = fmaxf(red[s_][h], red[s_ + st][h]);
    __syncthreads();
  }
  if (tid < 8) amaxS[tid] = red[0][tid];
  __syncthreads();

  // segment sum of exp
  float am = amaxS[h];
  float sm = 0.f;
  for (int i = s_; i < n; i += 32) {
    int e = elist[beg + i];
    sm += expf(raw[(size_t)e * 8 + h] - am);
  }
  red[s_][h] = sm;
  __syncthreads();
  #pragma unroll
  for (int st = 16; st >= 1; st >>= 1) {
    if (s_ < st) red[s_][h] += red[s_ + st][h];
    __syncthreads();
  }
  if (tid < 8) invS[tid] = 1.f / (red[0][tid] + 1e-16f);
  __syncthreads();

  // aggregation: out[r, h2*32+d] = sum_e beta[e,h2] * MSG[tail[e], h2*32+d]
  const int h2 = tid >> 5;
  const float am2 = amaxS[h2];
  const float iv = invS[h2];
  float acc = 0.f;
  int e0 = elist[beg], t0 = trip[e0 * 3 + 1];
  for (int i = 0; i < n; ++i) {
    int e = e0, tl = t0;
    if (i + 1 < n) {  // prefetch next indices to break the serial load chain
      e0 = elist[beg + i + 1];
      t0 = trip[e0 * 3 + 1];
    }
    float w = expf(raw[(size_t)e * 8 + h2] - am2) * iv;
    acc += w * P[(size_t)tl * NCOLS + 512 + tid];
  }
  out[(size_t)r * 256 + tid] = acc;
}

extern "C" void kernel_launch(void* const* d_in, const int* in_sizes, int n_in,
                              void* d_out, int out_size, void* d_ws, size_t ws_size,
                              hipStream_t stream) {
  const float* emb      = (const float*)d_in[0];
  const int*   trip     = (const int*)d_in[1];
  const float* attn_w   = (const float*)d_in[2];
  const float* attn_b   = (const float*)d_in[3];
  const float* attn_bin = (const float*)d_in[4];
  const float* attn_vec = (const float*)d_in[5];
  const float* aggr_w   = (const float*)d_in[6];
  const float* aggr_b   = (const float*)d_in[7];
  float* out = (float*)d_out;

  // workspace layout (~84.7 MB)
  float* P    = (float*)d_ws;                       // 20000*768 f32
  float* raw  = P + (size_t)NUM_REL * NCOLS;        // 640000*8 f32
  int* elist  = (int*)(raw + (size_t)NUM_EDGES * 8);// 640000 i32
  int* count  = elist + NUM_EDGES;                  // 20000 i32
  int* offs   = count + NUM_REL;                    // 20001 i32
  int* cursor = offs + NUM_REL + 1;                 // 20000 i32

  hipMemsetAsync(count, 0, NUM_REL * sizeof(int), stream);

  dim3 ggrid((NUM_REL + 127) / 128, NCOLS / 128);
  hipLaunchKernelGGL(gemm_kernel, ggrid, dim3(256), 0, stream,
                     emb, attn_w, attn_b, aggr_w, aggr_b, P);
  hipLaunchKernelGGL(edge_raw_kernel, dim3(4096), dim3(256), 0, stream,
                     P, trip, attn_bin, attn_vec, raw, count);
  hipLaunchKernelGGL(scan_kernel, dim3(1), dim3(1024), 0, stream,
                     count, offs, cursor);
  hipLaunchKernelGGL(fill_kernel, dim3((NUM_EDGES + 255) / 256), dim3(256), 0, stream,
                     trip, cursor, elist);
  hipLaunchKernelGGL(aggregate_kernel, dim3(NUM_REL), dim3(256), 0, stream,
                     P, trip, raw, offs, elist, out);
}

// Round 3
// 460.896 us; speedup vs baseline: 1.2835x; 1.2835x over previous
//
#include <hip/hip_runtime.h>
#include <cstdint>
#include <cstddef>

#define NUM_REL 20000
#define NUM_EDGES 640000
#define DIM_IN 128
#define DIM_OUT 256
#define NUM_HEAD 8
#define DIM_HID 32
#define NUM_BIN 10
#define NCOLS 768  // P row: [0,256)=ZH (W1*emb), [256,512)=ZT (W2*emb + attn_b), [512,768)=MSG (Wa*emb + aggr_b)

// ---------------------------------------------------------------------------
// Fused GEMM: P[r, :] = [emb@W1^T | emb@W2^T + attn_b | emb@Wa^T + aggr_b]
// BM=BN=128, BK=32, 256 threads, 8x8 per thread (split 4+4).
// ---------------------------------------------------------------------------
__global__ __launch_bounds__(256) void gemm_kernel(
    const float* __restrict__ emb, const float* __restrict__ attn_w,
    const float* __restrict__ attn_b, const float* __restrict__ aggr_w,
    const float* __restrict__ aggr_b, float* __restrict__ P) {
  __shared__ float As[32][132];  // [k][m]
  __shared__ float Bs[32][132];  // [k][n]
  const int tid = threadIdx.x;
  const int m0 = blockIdx.x * 128;
  const int n0 = blockIdx.y * 128;
  const int reg = n0 >> 8;  // 0: W1 (attn_w k 0..127), 1: W2 (attn_w k 128..255), 2: Wa
  const int ty = tid >> 4, tx = tid & 15;
  float acc[2][2][4][4] = {};

  for (int kk = 0; kk < 128; kk += 32) {
    #pragma unroll
    for (int j = 0; j < 4; ++j) {
      int c = tid + j * 256;
      int rown = c >> 3, kc = c & 7;
      int gm = m0 + rown;
      float4 av = make_float4(0.f, 0.f, 0.f, 0.f);
      if (gm < NUM_REL) av = *(const float4*)(emb + (size_t)gm * DIM_IN + kk + kc * 4);
      As[kc * 4 + 0][rown] = av.x; As[kc * 4 + 1][rown] = av.y;
      As[kc * 4 + 2][rown] = av.z; As[kc * 4 + 3][rown] = av.w;
      int o = n0 + rown;
      float4 bv;
      if (reg == 0)      bv = *(const float4*)(attn_w + (size_t)o * 256 + kk + kc * 4);
      else if (reg == 1) bv = *(const float4*)(attn_w + (size_t)(o - 256) * 256 + 128 + kk + kc * 4);
      else               bv = *(const float4*)(aggr_w + (size_t)(o - 512) * 128 + kk + kc * 4);
      Bs[kc * 4 + 0][rown] = bv.x; Bs[kc * 4 + 1][rown] = bv.y;
      Bs[kc * 4 + 2][rown] = bv.z; Bs[kc * 4 + 3][rown] = bv.w;
    }
    __syncthreads();
    #pragma unroll
    for (int k = 0; k < 32; ++k) {
      float4 a0 = *(const float4*)&As[k][ty * 4];
      float4 a1 = *(const float4*)&As[k][64 + ty * 4];
      float4 b0 = *(const float4*)&Bs[k][tx * 4];
      float4 b1 = *(const float4*)&Bs[k][64 + tx * 4];
      float am[2][4] = {{a0.x, a0.y, a0.z, a0.w}, {a1.x, a1.y, a1.z, a1.w}};
      float bn[2][4] = {{b0.x, b0.y, b0.z, b0.w}, {b1.x, b1.y, b1.z, b1.w}};
      #pragma unroll
      for (int im = 0; im < 2; ++im)
        #pragma unroll
        for (int in_ = 0; in_ < 2; ++in_)
          #pragma unroll
          for (int i = 0; i < 4; ++i)
            #pragma unroll
            for (int jj = 0; jj < 4; ++jj)
              acc[im][in_][i][jj] += am[im][i] * bn[in_][jj];
    }
    __syncthreads();
  }

  float bias[2][4];
  #pragma unroll
  for (int in_ = 0; in_ < 2; ++in_) {
    #pragma unroll
    for (int jj = 0; jj < 4; ++jj) {
      int gn = n0 + in_ * 64 + tx * 4 + jj;
      float b = 0.f;
      if (gn >= 512)      b = aggr_b[gn - 512];
      else if (gn >= 256) b = attn_b[gn - 256];
      bias[in_][jj] = b;
    }
  }
  #pragma unroll
  for (int im = 0; im < 2; ++im) {
    #pragma unroll
    for (int i = 0; i < 4; ++i) {
      int gm = m0 + im * 64 + ty * 4 + i;
      if (gm >= NUM_REL) continue;
      #pragma unroll
      for (int in_ = 0; in_ < 2; ++in_) {
        int gn = n0 + in_ * 64 + tx * 4;
        float4 v;
        v.x = acc[im][in_][i][0] + bias[in_][0];
        v.y = acc[im][in_][i][1] + bias[in_][1];
        v.z = acc[im][in_][i][2] + bias[in_][2];
        v.w = acc[im][in_][i][3] + bias[in_][3];
        *(float4*)(P + (size_t)gm * NCOLS + gn) = v;
      }
    }
  }
}

// ---------------------------------------------------------------------------
// Histogram of edges per head relation.
// ---------------------------------------------------------------------------
__global__ __launch_bounds__(256) void hist_kernel(
    const int* __restrict__ trip, int* __restrict__ count) {
  int e = blockIdx.x * 256 + threadIdx.x;
  if (e < NUM_EDGES) atomicAdd(&count[trip[e * 3]], 1);
}

// ---------------------------------------------------------------------------
// Exclusive scan of per-relation counts -> CSR offsets (+ cursor copy).
// ---------------------------------------------------------------------------
__global__ __launch_bounds__(1024) void scan_kernel(
    const int* __restrict__ count, int* __restrict__ offs, int* __restrict__ cursor) {
  __shared__ int s[1024];
  const int t = threadIdx.x;
  const int base = t * 20;
  int loc[20];
  int sum = 0;
  #pragma unroll
  for (int i = 0; i < 20; ++i) {
    int idx = base + i;
    int v = (idx < NUM_REL) ? count[idx] : 0;
    loc[i] = sum;
    sum += v;
  }
  s[t] = sum;
  __syncthreads();
  for (int off = 1; off < 1024; off <<= 1) {
    int v = 0;
    if (t >= off) v = s[t - off];
    __syncthreads();
    if (t >= off) s[t] += v;
    __syncthreads();
  }
  int prev = (t > 0) ? s[t - 1] : 0;
  #pragma unroll
  for (int i = 0; i < 20; ++i) {
    int idx = base + i;
    if (idx < NUM_REL) {
      int o = prev + loc[i];
      offs[idx] = o;
      cursor[idx] = o;
    }
  }
  if (t == 1023) offs[NUM_REL] = s[1023];
}

// ---------------------------------------------------------------------------
// Bucket fill: tbsorted[pos] = tail | (bin << 15), grouped by head relation.
// (tail < 32768, bin < 16 -> fits one int)
// ---------------------------------------------------------------------------
__global__ __launch_bounds__(256) void fill_kernel(
    const int* __restrict__ trip, int* __restrict__ cursor, int* __restrict__ tbsorted) {
  int e = blockIdx.x * 256 + threadIdx.x;
  if (e < NUM_EDGES) {
    int hd = trip[e * 3 + 0];
    int tl = trip[e * 3 + 1];
    int bn = trip[e * 3 + 2];
    int pos = atomicAdd(&cursor[hd], 1);
    tbsorted[pos] = tl | (bn << 15);
  }
}

// ---------------------------------------------------------------------------
// Attention logits, head-sorted: block = one head relation; ZH row loaded
// ONCE into registers; per edge only ZT[tail] is gathered (halves traffic).
// Writes rsorted[(beg+i)*8 + h] (coalesced consumption downstream).
// Lane l owns components 4l..4l+3 of the 256-wide z row (head h = l>>3).
// ---------------------------------------------------------------------------
__global__ __launch_bounds__(256) void edge_raw_kernel(
    const float* __restrict__ P, const int* __restrict__ tbsorted,
    const int* __restrict__ offs, const float* __restrict__ attn_bin,
    const float* __restrict__ attn_vec, float* __restrict__ rsorted) {
  const int r = blockIdx.x;
  const int beg = offs[r];
  const int n = offs[r + 1] - beg;
  if (n == 0) return;
  const int lane = threadIdx.x & 63;
  const int w = threadIdx.x >> 6;
  const float4 vv = *(const float4*)(attn_vec + lane * 4);
  const float4 zh = *(const float4*)(P + (size_t)r * NCOLS + lane * 4);
  for (int i = w; i < n; i += 4) {
    int tb = tbsorted[beg + i];
    int tl = tb & 0x7fff;
    int bn = tb >> 15;
    float4 zt = *(const float4*)(P + (size_t)tl * NCOLS + 256 + lane * 4);
    float zx = zh.x + zt.x, zy = zh.y + zt.y, zz = zh.z + zt.z, zw = zh.w + zt.w;
    zx = zx > 0.f ? zx : 0.2f * zx;
    zy = zy > 0.f ? zy : 0.2f * zy;
    zz = zz > 0.f ? zz : 0.2f * zz;
    zw = zw > 0.f ? zw : 0.2f * zw;
    float p = zx * vv.x + zy * vv.y + zz * vv.z + zw * vv.w;
    p += __shfl_xor(p, 1);
    p += __shfl_xor(p, 2);
    p += __shfl_xor(p, 4);  // lanes 8h hold the head-h partial dot
    if ((lane & 7) == 0) {
      int h = lane >> 3;
      rsorted[(size_t)(beg + i) * 8 + h] = p + attn_bin[bn * 8 + h];
    }
  }
}

// ---------------------------------------------------------------------------
// Per-relation softmax + weighted aggregation of MSG rows.
// Block = 256 threads = one relation. Softmax weights computed once per
// 64-edge chunk into LDS; MSG gather unrolled x4 (4 loads in flight).
// ---------------------------------------------------------------------------
__global__ __launch_bounds__(256) void aggregate_kernel(
    const float* __restrict__ P, const float* __restrict__ rsorted,
    const int* __restrict__ tbsorted, const int* __restrict__ offs,
    float* __restrict__ out) {
  const int r = blockIdx.x;
  const int tid = threadIdx.x;
  const int beg = offs[r];
  const int n = offs[r + 1] - beg;
  if (n == 0) {
    out[(size_t)r * 256 + tid] = 0.f;
    return;
  }
  __shared__ float red[32][8];
  __shared__ float amaxS[8], invS[8];
  __shared__ float wS[64][8];
  __shared__ int tS[64];
  const int s_ = tid >> 3, h = tid & 7;

  // segment max (coalesced over rsorted)
  float mx = -3.4e38f;
  for (int i = s_; i < n; i += 32)
    mx = fmaxf(mx, rsorted[(size_t)(beg + i) * 8 + h]);
  red[s_][h] = mx;
  __syncthreads();
  #pragma unroll
  for (int st = 16; st >= 1; st >>= 1) {
    if (s_ < st) red[s_][h] = fmaxf(red[s_][h], red[s_ + st][h]);
    __syncthreads();
  }
  if (tid < 8) amaxS[tid] = red[0][tid];
  __syncthreads();

  // segment sum of exp
  const float am = amaxS[h];
  float sm = 0.f;
  for (int i = s_; i < n; i += 32)
    sm += expf(rsorted[(size_t)(beg + i) * 8 + h] - am);
  red[s_][h] = sm;
  __syncthreads();
  #pragma unroll
  for (int st = 16; st >= 1; st >>= 1) {
    if (s_ < st) red[s_][h] += red[s_ + st][h];
    __syncthreads();
  }
  if (tid < 8) invS[tid] = 1.f / (red[0][tid] + 1e-16f);
  __syncthreads();

  // aggregation: out[r, h2*32+d] = sum_i w[i,h2] * MSG[tail_i][h2*32+d]
  const int h2 = tid >> 5;
  float acc0 = 0.f, acc1 = 0.f, acc2 = 0.f, acc3 = 0.f;
  for (int c0 = 0; c0 < n; c0 += 64) {
    const int cn = min(64, n - c0);
    for (int idx = tid; idx < cn * 8; idx += 256) {  // coalesced rsorted read
      int i = idx >> 3, hh = idx & 7;
      wS[i][hh] = expf(rsorted[(size_t)(beg + c0 + i) * 8 + hh] - amaxS[hh]) * invS[hh];
    }
    if (tid < cn) tS[tid] = tbsorted[beg + c0 + tid] & 0x7fff;
    __syncthreads();
    int i = 0;
    for (; i + 4 <= cn; i += 4) {
      int t0 = tS[i], t1 = tS[i + 1], t2 = tS[i + 2], t3 = tS[i + 3];
      float w0 = wS[i][h2], w1 = wS[i + 1][h2], w2 = wS[i + 2][h2], w3 = wS[i + 3][h2];
      acc0 += w0 * P[(size_t)t0 * NCOLS + 512 + tid];
      acc1 += w1 * P[(size_t)t1 * NCOLS + 512 + tid];
      acc2 += w2 * P[(size_t)t2 * NCOLS + 512 + tid];
      acc3 += w3 * P[(size_t)t3 * NCOLS + 512 + tid];
    }
    for (; i < cn; ++i)
      acc0 += wS[i][h2] * P[(size_t)tS[i] * NCOLS + 512 + tid];
    __syncthreads();
  }
  out[(size_t)r * 256 + tid] = acc0 + acc1 + acc2 + acc3;
}

extern "C" void kernel_launch(void* const* d_in, const int* in_sizes, int n_in,
                              void* d_out, int out_size, void* d_ws, size_t ws_size,
                              hipStream_t stream) {
  const float* emb      = (const float*)d_in[0];
  const int*   trip     = (const int*)d_in[1];
  const float* attn_w   = (const float*)d_in[2];
  const float* attn_b   = (const float*)d_in[3];
  const float* attn_bin = (const float*)d_in[4];
  const float* attn_vec = (const float*)d_in[5];
  const float* aggr_w   = (const float*)d_in[6];
  const float* aggr_b   = (const float*)d_in[7];
  float* out = (float*)d_out;

  // workspace layout (~84.6 MB)
  float* P       = (float*)d_ws;                         // 20000*768 f32
  float* rsorted = P + (size_t)NUM_REL * NCOLS;          // 640000*8 f32 (head-sorted raw)
  int* tbsorted  = (int*)(rsorted + (size_t)NUM_EDGES * 8); // 640000 i32 (tail | bin<<15)
  int* count     = tbsorted + NUM_EDGES;                 // 20000 i32
  int* offs      = count + NUM_REL;                      // 20001 i32
  int* cursor    = offs + NUM_REL + 1;                   // 20000 i32

  hipMemsetAsync(count, 0, NUM_REL * sizeof(int), stream);

  dim3 ggrid((NUM_REL + 127) / 128, NCOLS / 128);
  hipLaunchKernelGGL(gemm_kernel, ggrid, dim3(256), 0, stream,
                     emb, attn_w, attn_b, aggr_w, aggr_b, P);
  hipLaunchKernelGGL(hist_kernel, dim3((NUM_EDGES + 255) / 256), dim3(256), 0, stream,
                     trip, count);
  hipLaunchKernelGGL(scan_kernel, dim3(1), dim3(1024), 0, stream,
                     count, offs, cursor);
  hipLaunchKernelGGL(fill_kernel, dim3((NUM_EDGES + 255) / 256), dim3(256), 0, stream,
                     trip, cursor, tbsorted);
  hipLaunchKernelGGL(edge_raw_kernel, dim3(NUM_REL), dim3(256), 0, stream,
                     P, tbsorted, offs, attn_bin, attn_vec, rsorted);
  hipLaunchKernelGGL(aggregate_kernel, dim3(NUM_REL), dim3(256), 0, stream,
                     P, rsorted, tbsorted, offs, out);
}

// Round 4
// 399.032 us; speedup vs baseline: 1.4825x; 1.1550x over previous
//
#include <hip/hip_runtime.h>
#include <cstdint>
#include <cstddef>

#define NUM_REL 20000
#define NUM_EDGES 640000
#define DIM_IN 128
#define DIM_OUT 256
#define NUM_HEAD 8
#define DIM_HID 32
#define NUM_BIN 10
#define NCOLS 768   // P row: [0,256)=ZH, [256,512)=ZT (+attn_b), [512,768)=MSG (+aggr_b)
#define RAWCAP 512  // per-relation LDS raw capacity (data max degree ~60; global fallback beyond)

// ---------------------------------------------------------------------------
// Fused GEMM: P[r, :] = [emb@W1^T | emb@W2^T + attn_b | emb@Wa^T + aggr_b]
// BM=BN=64, BK=32, 256 threads, 4x4 per thread. Small tiles -> 3756 blocks,
// low VGPR/LDS -> high occupancy (round-3 config was ~1 block/CU, 10% occ).
// ---------------------------------------------------------------------------
__global__ __launch_bounds__(256) void gemm_kernel(
    const float* __restrict__ emb, const float* __restrict__ attn_w,
    const float* __restrict__ attn_b, const float* __restrict__ aggr_w,
    const float* __restrict__ aggr_b, float* __restrict__ P) {
  __shared__ float As[32][68];  // [k][m]
  __shared__ float Bs[32][68];  // [k][n]
  const int tid = threadIdx.x;
  const int m0 = blockIdx.x * 64;
  const int n0 = blockIdx.y * 64;
  const int reg = n0 >> 8;  // 0: W1, 1: W2, 2: Wa
  const int ty = tid >> 4, tx = tid & 15;
  float acc[4][4] = {};

  for (int kk = 0; kk < 128; kk += 32) {
    #pragma unroll
    for (int j = 0; j < 2; ++j) {
      int c = tid + j * 256;       // 0..511 float4 chunks (64 rows x 8 k-chunks)
      int rown = c >> 3, kc = c & 7;
      int gm = m0 + rown;
      float4 av = make_float4(0.f, 0.f, 0.f, 0.f);
      if (gm < NUM_REL) av = *(const float4*)(emb + (size_t)gm * DIM_IN + kk + kc * 4);
      As[kc * 4 + 0][rown] = av.x; As[kc * 4 + 1][rown] = av.y;
      As[kc * 4 + 2][rown] = av.z; As[kc * 4 + 3][rown] = av.w;
      int o = n0 + rown;
      float4 bv;
      if (reg == 0)      bv = *(const float4*)(attn_w + (size_t)o * 256 + kk + kc * 4);
      else if (reg == 1) bv = *(const float4*)(attn_w + (size_t)(o - 256) * 256 + 128 + kk + kc * 4);
      else               bv = *(const float4*)(aggr_w + (size_t)(o - 512) * 128 + kk + kc * 4);
      Bs[kc * 4 + 0][rown] = bv.x; Bs[kc * 4 + 1][rown] = bv.y;
      Bs[kc * 4 + 2][rown] = bv.z; Bs[kc * 4 + 3][rown] = bv.w;
    }
    __syncthreads();
    #pragma unroll
    for (int k = 0; k < 32; ++k) {
      float4 a4 = *(const float4*)&As[k][ty * 4];
      float4 b4 = *(const float4*)&Bs[k][tx * 4];
      float am[4] = {a4.x, a4.y, a4.z, a4.w};
      float bn[4] = {b4.x, b4.y, b4.z, b4.w};
      #pragma unroll
      for (int i = 0; i < 4; ++i)
        #pragma unroll
        for (int jj = 0; jj < 4; ++jj)
          acc[i][jj] += am[i] * bn[jj];
    }
    __syncthreads();
  }

  float bias[4];
  #pragma unroll
  for (int jj = 0; jj < 4; ++jj) {
    int gn = n0 + tx * 4 + jj;
    float b = 0.f;
    if (gn >= 512)      b = aggr_b[gn - 512];
    else if (gn >= 256) b = attn_b[gn - 256];
    bias[jj] = b;
  }
  #pragma unroll
  for (int i = 0; i < 4; ++i) {
    int gm = m0 + ty * 4 + i;
    if (gm >= NUM_REL) continue;
    float4 v;
    v.x = acc[i][0] + bias[0];
    v.y = acc[i][1] + bias[1];
    v.z = acc[i][2] + bias[2];
    v.w = acc[i][3] + bias[3];
    *(float4*)(P + (size_t)gm * NCOLS + n0 + tx * 4) = v;
  }
}

// ---------------------------------------------------------------------------
// Histogram of edges per head relation.
// ---------------------------------------------------------------------------
__global__ __launch_bounds__(256) void hist_kernel(
    const int* __restrict__ trip, int* __restrict__ count) {
  int e = blockIdx.x * 256 + threadIdx.x;
  if (e < NUM_EDGES) atomicAdd(&count[trip[e * 3]], 1);
}

// ---------------------------------------------------------------------------
// Exclusive scan of per-relation counts -> CSR offsets (+ cursor copy).
// ---------------------------------------------------------------------------
__global__ __launch_bounds__(1024) void scan_kernel(
    const int* __restrict__ count, int* __restrict__ offs, int* __restrict__ cursor) {
  __shared__ int s[1024];
  const int t = threadIdx.x;
  const int base = t * 20;
  int loc[20];
  int sum = 0;
  #pragma unroll
  for (int i = 0; i < 20; ++i) {
    int idx = base + i;
    int v = (idx < NUM_REL) ? count[idx] : 0;
    loc[i] = sum;
    sum += v;
  }
  s[t] = sum;
  __syncthreads();
  for (int off = 1; off < 1024; off <<= 1) {
    int v = 0;
    if (t >= off) v = s[t - off];
    __syncthreads();
    if (t >= off) s[t] += v;
    __syncthreads();
  }
  int prev = (t > 0) ? s[t - 1] : 0;
  #pragma unroll
  for (int i = 0; i < 20; ++i) {
    int idx = base + i;
    if (idx < NUM_REL) {
      int o = prev + loc[i];
      offs[idx] = o;
      cursor[idx] = o;
    }
  }
  if (t == 1023) offs[NUM_REL] = s[1023];
}

// ---------------------------------------------------------------------------
// Bucket fill: tbsorted[pos] = tail | (bin << 15), grouped by head relation.
// ---------------------------------------------------------------------------
__global__ __launch_bounds__(256) void fill_kernel(
    const int* __restrict__ trip, int* __restrict__ cursor, int* __restrict__ tbsorted) {
  int e = blockIdx.x * 256 + threadIdx.x;
  if (e < NUM_EDGES) {
    int hd = trip[e * 3 + 0];
    int tl = trip[e * 3 + 1];
    int bn = trip[e * 3 + 2];
    int pos = atomicAdd(&cursor[hd], 1);
    tbsorted[pos] = tl | (bn << 15);
  }
}

// ---------------------------------------------------------------------------
// Fused per-relation: logits (ZT gather) -> in-LDS softmax -> weighted MSG
// gather. Block = 256 threads = one relation. Phase A: wave per edge, lane l
// owns z components 4l..4l+3 (head = l>>3); raw kept in LDS (<=RAWCAP) or
// spilled to rawG. Phase B: thread owns out column tid, x4-unrolled gather.
// ---------------------------------------------------------------------------
__global__ __launch_bounds__(256) void edge_agg_kernel(
    const float* __restrict__ P, const int* __restrict__ tbsorted,
    const int* __restrict__ offs, const float* __restrict__ attn_bin,
    const float* __restrict__ attn_vec, float* __restrict__ rawG,
    float* __restrict__ out) {
  const int r = blockIdx.x;
  const int tid = threadIdx.x;
  const int beg = offs[r];
  const int n = offs[r + 1] - beg;
  if (n == 0) {
    out[(size_t)r * 256 + tid] = 0.f;
    return;
  }
  __shared__ float rawS[RAWCAP][8];  // raw logits, later softmax weights
  __shared__ int tS[RAWCAP];
  __shared__ float red[32][8];
  __shared__ float amaxS[8], invS[8];
  const int lane = tid & 63;
  const int w = tid >> 6;

  // ---- phase A: attention logits ----
  {
    const float4 vv = *(const float4*)(attn_vec + lane * 4);
    const float4 zh = *(const float4*)(P + (size_t)r * NCOLS + lane * 4);
    int tbn = (w < n) ? tbsorted[beg + w] : 0;
    for (int i = w; i < n; i += 4) {
      int tb = tbn;
      if (i + 4 < n) tbn = tbsorted[beg + i + 4];  // prefetch, break dep chain
      int tl = tb & 0x7fff;
      int bn = tb >> 15;
      if (lane == 0 && i < RAWCAP) tS[i] = tl;
      float4 zt = *(const float4*)(P + (size_t)tl * NCOLS + 256 + lane * 4);
      float zx = zh.x + zt.x, zy = zh.y + zt.y, zz = zh.z + zt.z, zw = zh.w + zt.w;
      zx = zx > 0.f ? zx : 0.2f * zx;
      zy = zy > 0.f ? zy : 0.2f * zy;
      zz = zz > 0.f ? zz : 0.2f * zz;
      zw = zw > 0.f ? zw : 0.2f * zw;
      float p = zx * vv.x + zy * vv.y + zz * vv.z + zw * vv.w;
      p += __shfl_xor(p, 1);
      p += __shfl_xor(p, 2);
      p += __shfl_xor(p, 4);  // lanes 8h hold head-h dot
      if ((lane & 7) == 0) {
        int h = lane >> 3;
        float val = p + attn_bin[bn * 8 + h];
        if (i < RAWCAP) rawS[i][h] = val;
        else            rawG[(size_t)(beg + i) * 8 + h] = val;
      }
    }
  }
  __syncthreads();

  // ---- softmax stats ----
  const int s_ = tid >> 3, h = tid & 7;
  float mx = -3.4e38f;
  for (int i = s_; i < n; i += 32)
    mx = fmaxf(mx, (i < RAWCAP) ? rawS[i][h] : rawG[(size_t)(beg + i) * 8 + h]);
  red[s_][h] = mx;
  __syncthreads();
  #pragma unroll
  for (int st = 16; st >= 1; st >>= 1) {
    if (s_ < st) red[s_][h] = fmaxf(red[s_][h], red[s_ + st][h]);
    __syncthreads();
  }
  if (tid < 8) amaxS[tid] = red[0][tid];
  __syncthreads();
  const float am = amaxS[h];
  float sm = 0.f;
  for (int i = s_; i < n; i += 32)
    sm += expf(((i < RAWCAP) ? rawS[i][h] : rawG[(size_t)(beg + i) * 8 + h]) - am);
  red[s_][h] = sm;
  __syncthreads();
  #pragma unroll
  for (int st = 16; st >= 1; st >>= 1) {
    if (s_ < st) red[s_][h] += red[s_ + st][h];
    __syncthreads();
  }
  if (tid < 8) invS[tid] = 1.f / (red[0][tid] + 1e-16f);
  __syncthreads();

  // convert LDS raw -> softmax weight in place
  const int nc = (n < RAWCAP) ? n : RAWCAP;
  for (int idx = tid; idx < nc * 8; idx += 256) {
    int i = idx >> 3, hh = idx & 7;
    rawS[i][hh] = expf(rawS[i][hh] - amaxS[hh]) * invS[hh];
  }
  __syncthreads();

  // ---- phase B: weighted MSG gather ----
  const int h2 = tid >> 5;
  float acc0 = 0.f, acc1 = 0.f, acc2 = 0.f, acc3 = 0.f;
  int i = 0;
  for (; i + 4 <= nc; i += 4) {
    int t0 = tS[i], t1 = tS[i + 1], t2 = tS[i + 2], t3 = tS[i + 3];
    float w0 = rawS[i][h2], w1 = rawS[i + 1][h2], w2 = rawS[i + 2][h2], w3 = rawS[i + 3][h2];
    acc0 += w0 * P[(size_t)t0 * NCOLS + 512 + tid];
    acc1 += w1 * P[(size_t)t1 * NCOLS + 512 + tid];
    acc2 += w2 * P[(size_t)t2 * NCOLS + 512 + tid];
    acc3 += w3 * P[(size_t)t3 * NCOLS + 512 + tid];
  }
  for (; i < nc; ++i)
    acc0 += rawS[i][h2] * P[(size_t)tS[i] * NCOLS + 512 + tid];
  for (; i < n; ++i) {  // rare fallback path (n > RAWCAP)
    int tl = tbsorted[beg + i] & 0x7fff;
    float wgt = expf(rawG[(size_t)(beg + i) * 8 + h2] - amaxS[h2]) * invS[h2];
    acc0 += wgt * P[(size_t)tl * NCOLS + 512 + tid];
  }
  out[(size_t)r * 256 + tid] = acc0 + acc1 + acc2 + acc3;
}

extern "C" void kernel_launch(void* const* d_in, const int* in_sizes, int n_in,
                              void* d_out, int out_size, void* d_ws, size_t ws_size,
                              hipStream_t stream) {
  const float* emb      = (const float*)d_in[0];
  const int*   trip     = (const int*)d_in[1];
  const float* attn_w   = (const float*)d_in[2];
  const float* attn_b   = (const float*)d_in[3];
  const float* attn_bin = (const float*)d_in[4];
  const float* attn_vec = (const float*)d_in[5];
  const float* aggr_w   = (const float*)d_in[6];
  const float* aggr_b   = (const float*)d_in[7];
  float* out = (float*)d_out;

  // workspace layout (~84.6 MB)
  float* P      = (float*)d_ws;                          // 20000*768 f32
  float* rawG   = P + (size_t)NUM_REL * NCOLS;           // 640000*8 f32 (fallback only)
  int* tbsorted = (int*)(rawG + (size_t)NUM_EDGES * 8);  // 640000 i32 (tail | bin<<15)
  int* count    = tbsorted + NUM_EDGES;                  // 20000 i32
  int* offs     = count + NUM_REL;                       // 20001 i32
  int* cursor   = offs + NUM_REL + 1;                    // 20000 i32

  hipMemsetAsync(count, 0, NUM_REL * sizeof(int), stream);

  dim3 ggrid((NUM_REL + 63) / 64, NCOLS / 64);
  hipLaunchKernelGGL(gemm_kernel, ggrid, dim3(256), 0, stream,
                     emb, attn_w, attn_b, aggr_w, aggr_b, P);
  hipLaunchKernelGGL(hist_kernel, dim3((NUM_EDGES + 255) / 256), dim3(256), 0, stream,
                     trip, count);
  hipLaunchKernelGGL(scan_kernel, dim3(1), dim3(1024), 0, stream,
                     count, offs, cursor);
  hipLaunchKernelGGL(fill_kernel, dim3((NUM_EDGES + 255) / 256), dim3(256), 0, stream,
                     trip, cursor, tbsorted);
  hipLaunchKernelGGL(edge_agg_kernel, dim3(NUM_REL), dim3(256), 0, stream,
                     P, tbsorted, offs, attn_bin, attn_vec, rawG, out);
}

// Round 5
// 389.876 us; speedup vs baseline: 1.5173x; 1.0235x over previous
//
#include <hip/hip_runtime.h>
#include <cstdint>
#include <cstddef>

#define NUM_REL 20000
#define NUM_EDGES 640000
#define DIM_IN 128
#define DIM_OUT 256
#define NUM_HEAD 8
#define DIM_HID 32
#define NUM_BIN 10
#define NCOLS 768   // P row: [0,256)=ZH, [256,512)=ZT (+attn_b), [512,768)=MSG (+aggr_b)
#define RAWCAP 128  // per-relation LDS capacity (max degree ~65 for this data; global fallback beyond)

// ---------------------------------------------------------------------------
// Fused GEMM: P[r, :] = [emb@W1^T | emb@W2^T + attn_b | emb@Wa^T + aggr_b]
// BM=BN=64, BK=32, 256 threads, 4x4 per thread.
// ---------------------------------------------------------------------------
__global__ __launch_bounds__(256) void gemm_kernel(
    const float* __restrict__ emb, const float* __restrict__ attn_w,
    const float* __restrict__ attn_b, const float* __restrict__ aggr_w,
    const float* __restrict__ aggr_b, float* __restrict__ P) {
  __shared__ float As[32][68];  // [k][m]
  __shared__ float Bs[32][68];  // [k][n]
  const int tid = threadIdx.x;
  const int m0 = blockIdx.x * 64;
  const int n0 = blockIdx.y * 64;
  const int reg = n0 >> 8;  // 0: W1, 1: W2, 2: Wa
  const int ty = tid >> 4, tx = tid & 15;
  float acc[4][4] = {};

  for (int kk = 0; kk < 128; kk += 32) {
    #pragma unroll
    for (int j = 0; j < 2; ++j) {
      int c = tid + j * 256;       // 0..511 float4 chunks (64 rows x 8 k-chunks)
      int rown = c >> 3, kc = c & 7;
      int gm = m0 + rown;
      float4 av = make_float4(0.f, 0.f, 0.f, 0.f);
      if (gm < NUM_REL) av = *(const float4*)(emb + (size_t)gm * DIM_IN + kk + kc * 4);
      As[kc * 4 + 0][rown] = av.x; As[kc * 4 + 1][rown] = av.y;
      As[kc * 4 + 2][rown] = av.z; As[kc * 4 + 3][rown] = av.w;
      int o = n0 + rown;
      float4 bv;
      if (reg == 0)      bv = *(const float4*)(attn_w + (size_t)o * 256 + kk + kc * 4);
      else if (reg == 1) bv = *(const float4*)(attn_w + (size_t)(o - 256) * 256 + 128 + kk + kc * 4);
      else               bv = *(const float4*)(aggr_w + (size_t)(o - 512) * 128 + kk + kc * 4);
      Bs[kc * 4 + 0][rown] = bv.x; Bs[kc * 4 + 1][rown] = bv.y;
      Bs[kc * 4 + 2][rown] = bv.z; Bs[kc * 4 + 3][rown] = bv.w;
    }
    __syncthreads();
    #pragma unroll
    for (int k = 0; k < 32; ++k) {
      float4 a4 = *(const float4*)&As[k][ty * 4];
      float4 b4 = *(const float4*)&Bs[k][tx * 4];
      float am[4] = {a4.x, a4.y, a4.z, a4.w};
      float bn[4] = {b4.x, b4.y, b4.z, b4.w};
      #pragma unroll
      for (int i = 0; i < 4; ++i)
        #pragma unroll
        for (int jj = 0; jj < 4; ++jj)
          acc[i][jj] += am[i] * bn[jj];
    }
    __syncthreads();
  }

  float bias[4];
  #pragma unroll
  for (int jj = 0; jj < 4; ++jj) {
    int gn = n0 + tx * 4 + jj;
    float b = 0.f;
    if (gn >= 512)      b = aggr_b[gn - 512];
    else if (gn >= 256) b = attn_b[gn - 256];
    bias[jj] = b;
  }
  #pragma unroll
  for (int i = 0; i < 4; ++i) {
    int gm = m0 + ty * 4 + i;
    if (gm >= NUM_REL) continue;
    float4 v;
    v.x = acc[i][0] + bias[0];
    v.y = acc[i][1] + bias[1];
    v.z = acc[i][2] + bias[2];
    v.w = acc[i][3] + bias[3];
    *(float4*)(P + (size_t)gm * NCOLS + n0 + tx * 4) = v;
  }
}

// ---------------------------------------------------------------------------
// Histogram of edges per head relation.
// ---------------------------------------------------------------------------
__global__ __launch_bounds__(256) void hist_kernel(
    const int* __restrict__ trip, int* __restrict__ count) {
  int e = blockIdx.x * 256 + threadIdx.x;
  if (e < NUM_EDGES) atomicAdd(&count[trip[e * 3]], 1);
}

// ---------------------------------------------------------------------------
// Exclusive scan of per-relation counts -> CSR offsets (+ cursor copy).
// ---------------------------------------------------------------------------
__global__ __launch_bounds__(1024) void scan_kernel(
    const int* __restrict__ count, int* __restrict__ offs, int* __restrict__ cursor) {
  __shared__ int s[1024];
  const int t = threadIdx.x;
  const int base = t * 20;
  int loc[20];
  int sum = 0;
  #pragma unroll
  for (int i = 0; i < 20; ++i) {
    int idx = base + i;
    int v = (idx < NUM_REL) ? count[idx] : 0;
    loc[i] = sum;
    sum += v;
  }
  s[t] = sum;
  __syncthreads();
  for (int off = 1; off < 1024; off <<= 1) {
    int v = 0;
    if (t >= off) v = s[t - off];
    __syncthreads();
    if (t >= off) s[t] += v;
    __syncthreads();
  }
  int prev = (t > 0) ? s[t - 1] : 0;
  #pragma unroll
  for (int i = 0; i < 20; ++i) {
    int idx = base + i;
    if (idx < NUM_REL) {
      int o = prev + loc[i];
      offs[idx] = o;
      cursor[idx] = o;
    }
  }
  if (t == 1023) offs[NUM_REL] = s[1023];
}

// ---------------------------------------------------------------------------
// Bucket fill: tbsorted[pos] = tail | (bin << 15), grouped by head relation.
// ---------------------------------------------------------------------------
__global__ __launch_bounds__(256) void fill_kernel(
    const int* __restrict__ trip, int* __restrict__ cursor, int* __restrict__ tbsorted) {
  int e = blockIdx.x * 256 + threadIdx.x;
  if (e < NUM_EDGES) {
    int hd = trip[e * 3 + 0];
    int tl = trip[e * 3 + 1];
    int bn = trip[e * 3 + 2];
    int pos = atomicAdd(&cursor[hd], 1);
    tbsorted[pos] = tl | (bn << 15);
  }
}

// ---------------------------------------------------------------------------
// Fused per-relation: logits (ZT gather, software-pipelined) -> in-LDS
// softmax -> weighted MSG gather (wave-per-edge float4, x2 unrolled).
// Block = 256 threads = one relation.
// ---------------------------------------------------------------------------
__global__ __launch_bounds__(256) void edge_agg_kernel(
    const float* __restrict__ P, const int* __restrict__ tbsorted,
    const int* __restrict__ offs, const float* __restrict__ attn_bin,
    const float* __restrict__ attn_vec, float* __restrict__ rawG,
    float* __restrict__ out) {
  const int r = blockIdx.x;
  const int tid = threadIdx.x;
  const int beg = offs[r];
  const int n = offs[r + 1] - beg;
  if (n == 0) {
    out[(size_t)r * 256 + tid] = 0.f;
    return;
  }
  __shared__ float rawS[RAWCAP][8];  // raw logits, later softmax weights
  __shared__ int tS[RAWCAP];
  __shared__ float red[32][8];
  __shared__ float redS[4][256];
  __shared__ float amaxS[8], invS[8];
  const int lane = tid & 63;
  const int w = tid >> 6;

  // ---- phase A: attention logits (pipelined: tails 2 ahead, row 1 ahead) ----
  {
    const float4 vv = *(const float4*)(attn_vec + lane * 4);
    const float4 zh = *(const float4*)(P + (size_t)r * NCOLS + lane * 4);
    int tb0 = (w < n) ? tbsorted[beg + w] : 0;
    int tb1 = (w + 4 < n) ? tbsorted[beg + w + 4] : 0;
    float4 zt0 = make_float4(0.f, 0.f, 0.f, 0.f);
    if (w < n) zt0 = *(const float4*)(P + (size_t)(tb0 & 0x7fff) * NCOLS + 256 + lane * 4);
    for (int i = w; i < n; i += 4) {
      int tb2 = (i + 8 < n) ? tbsorted[beg + i + 8] : 0;
      float4 zt1 = zt0;
      if (i + 4 < n) zt1 = *(const float4*)(P + (size_t)(tb1 & 0x7fff) * NCOLS + 256 + lane * 4);
      int tl = tb0 & 0x7fff;
      int bn = tb0 >> 15;
      if (lane == 0 && i < RAWCAP) tS[i] = tl;
      float zx = zh.x + zt0.x, zy = zh.y + zt0.y, zz = zh.z + zt0.z, zw = zh.w + zt0.w;
      zx = zx > 0.f ? zx : 0.2f * zx;
      zy = zy > 0.f ? zy : 0.2f * zy;
      zz = zz > 0.f ? zz : 0.2f * zz;
      zw = zw > 0.f ? zw : 0.2f * zw;
      float p = zx * vv.x + zy * vv.y + zz * vv.z + zw * vv.w;
      p += __shfl_xor(p, 1);
      p += __shfl_xor(p, 2);
      p += __shfl_xor(p, 4);  // lanes 8h hold head-h dot
      if ((lane & 7) == 0) {
        int h = lane >> 3;
        float val = p + attn_bin[bn * 8 + h];
        if (i < RAWCAP) rawS[i][h] = val;
        else            rawG[(size_t)(beg + i) * 8 + h] = val;
      }
      tb0 = tb1; tb1 = tb2; zt0 = zt1;
    }
  }
  __syncthreads();

  // ---- softmax stats ----
  const int s_ = tid >> 3, h = tid & 7;
  float mx = -3.4e38f;
  for (int i = s_; i < n; i += 32)
    mx = fmaxf(mx, (i < RAWCAP) ? rawS[i][h] : rawG[(size_t)(beg + i) * 8 + h]);
  red[s_][h] = mx;
  __syncthreads();
  #pragma unroll
  for (int st = 16; st >= 1; st >>= 1) {
    if (s_ < st) red[s_][h] = fmaxf(red[s_][h], red[s_ + st][h]);
    __syncthreads();
  }
  if (tid < 8) amaxS[tid] = red[0][tid];
  __syncthreads();
  const float am = amaxS[h];
  float sm = 0.f;
  for (int i = s_; i < n; i += 32)
    sm += expf(((i < RAWCAP) ? rawS[i][h] : rawG[(size_t)(beg + i) * 8 + h]) - am);
  red[s_][h] = sm;
  __syncthreads();
  #pragma unroll
  for (int st = 16; st >= 1; st >>= 1) {
    if (s_ < st) red[s_][h] += red[s_ + st][h];
    __syncthreads();
  }
  if (tid < 8) invS[tid] = 1.f / (red[0][tid] + 1e-16f);
  __syncthreads();

  // convert LDS raw -> softmax weight in place
  const int nc = (n < RAWCAP) ? n : RAWCAP;
  for (int idx = tid; idx < nc * 8; idx += 256) {
    int i = idx >> 3, hh = idx & 7;
    rawS[i][hh] = expf(rawS[i][hh] - amaxS[hh]) * invS[hh];
  }
  __syncthreads();

  // ---- phase B: weighted MSG gather, wave-per-edge, float4, x2 unroll ----
  // lane covers out columns 4*lane..4*lane+3, all in head lane>>3.
  {
    const int hB = lane >> 3;
    const float* __restrict__ Pm = P + 512 + lane * 4;
    float4 a0 = make_float4(0.f, 0.f, 0.f, 0.f);
    float4 a1 = make_float4(0.f, 0.f, 0.f, 0.f);
    int i = w;
    for (; i + 4 < nc; i += 8) {
      int t0 = tS[i], t1 = tS[i + 4];
      float w0 = rawS[i][hB], w1 = rawS[i + 4][hB];
      float4 m0 = *(const float4*)(Pm + (size_t)t0 * NCOLS);
      float4 m1 = *(const float4*)(Pm + (size_t)t1 * NCOLS);
      a0.x += w0 * m0.x; a0.y += w0 * m0.y; a0.z += w0 * m0.z; a0.w += w0 * m0.w;
      a1.x += w1 * m1.x; a1.y += w1 * m1.y; a1.z += w1 * m1.z; a1.w += w1 * m1.w;
    }
    for (; i < nc; i += 4) {
      int t0 = tS[i];
      float w0 = rawS[i][hB];
      float4 m0 = *(const float4*)(Pm + (size_t)t0 * NCOLS);
      a0.x += w0 * m0.x; a0.y += w0 * m0.y; a0.z += w0 * m0.z; a0.w += w0 * m0.w;
    }
    for (; i < n; i += 4) {  // rare fallback (n > RAWCAP)
      int tb = tbsorted[beg + i];
      int t0 = tb & 0x7fff;
      float w0 = expf(rawG[(size_t)(beg + i) * 8 + hB] - amaxS[hB]) * invS[hB];
      float4 m0 = *(const float4*)(Pm + (size_t)t0 * NCOLS);
      a0.x += w0 * m0.x; a0.y += w0 * m0.y; a0.z += w0 * m0.z; a0.w += w0 * m0.w;
    }
    a0.x += a1.x; a0.y += a1.y; a0.z += a1.z; a0.w += a1.w;
    *(float4*)&redS[w][lane * 4] = a0;
  }
  __syncthreads();
  out[(size_t)r * 256 + tid] = redS[0][tid] + redS[1][tid] + redS[2][tid] + redS[3][tid];
}

extern "C" void kernel_launch(void* const* d_in, const int* in_sizes, int n_in,
                              void* d_out, int out_size, void* d_ws, size_t ws_size,
                              hipStream_t stream) {
  const float* emb      = (const float*)d_in[0];
  const int*   trip     = (const int*)d_in[1];
  const float* attn_w   = (const float*)d_in[2];
  const float* attn_b   = (const float*)d_in[3];
  const float* attn_bin = (const float*)d_in[4];
  const float* attn_vec = (const float*)d_in[5];
  const float* aggr_w   = (const float*)d_in[6];
  const float* aggr_b   = (const float*)d_in[7];
  float* out = (float*)d_out;

  // workspace layout (~84.6 MB)
  float* P      = (float*)d_ws;                          // 20000*768 f32
  float* rawG   = P + (size_t)NUM_REL * NCOLS;           // 640000*8 f32 (fallback only)
  int* tbsorted = (int*)(rawG + (size_t)NUM_EDGES * 8);  // 640000 i32 (tail | bin<<15)
  int* count    = tbsorted + NUM_EDGES;                  // 20000 i32
  int* offs     = count + NUM_REL;                       // 20001 i32
  int* cursor   = offs + NUM_REL + 1;                    // 20000 i32

  hipMemsetAsync(count, 0, NUM_REL * sizeof(int), stream);

  dim3 ggrid((NUM_REL + 63) / 64, NCOLS / 64);
  hipLaunchKernelGGL(gemm_kernel, ggrid, dim3(256), 0, stream,
                     emb, attn_w, attn_b, aggr_w, aggr_b, P);
  hipLaunchKernelGGL(hist_kernel, dim3((NUM_EDGES + 255) / 256), dim3(256), 0, stream,
                     trip, count);
  hipLaunchKernelGGL(scan_kernel, dim3(1), dim3(1024), 0, stream,
                     count, offs, cursor);
  hipLaunchKernelGGL(fill_kernel, dim3((NUM_EDGES + 255) / 256), dim3(256), 0, stream,
                     trip, cursor, tbsorted);
  hipLaunchKernelGGL(edge_agg_kernel, dim3(NUM_REL), dim3(256), 0, stream,
                     P, tbsorted, offs, attn_bin, attn_vec, rawG, out);
}

// Round 6
// 337.565 us; speedup vs baseline: 1.7524x; 1.1550x over previous
//
#include <hip/hip_runtime.h>
#include <hip/hip_fp16.h>
#include <cstdint>
#include <cstddef>

#define NUM_REL 20000
#define NUM_EDGES 640000
#define DIM_IN 128
#define DIM_OUT 256
#define NUM_HEAD 8
#define DIM_HID 32
#define NUM_BIN 10
#define RAWCAP 128  // per-relation LDS capacity (max degree ~65 here; global fallback beyond)

// P split: Pz[r][0..256) = ZH (fp32, read once per relation)
//          Ph[r][0..256) = ZT (+attn_b) fp16 ; Ph[r][256..512) = MSG (+aggr_b) fp16
// fp16 halves the per-edge gather (2 KB -> 1 KB) and doubles L2 row capacity.

// ---------------------------------------------------------------------------
// Fused GEMM: cols [0,256)=emb@W1^T -> Pz ; [256,512)=emb@W2^T+attn_b -> Ph ZT ;
// [512,768)=emb@Wa^T+aggr_b -> Ph MSG. BM=BN=64, BK=32, 256 thr, 4x4/thread.
// ---------------------------------------------------------------------------
__global__ __launch_bounds__(256) void gemm_kernel(
    const float* __restrict__ emb, const float* __restrict__ attn_w,
    const float* __restrict__ attn_b, const float* __restrict__ aggr_w,
    const float* __restrict__ aggr_b, float* __restrict__ Pz,
    __half* __restrict__ Ph) {
  __shared__ float As[32][68];  // [k][m]
  __shared__ float Bs[32][68];  // [k][n]
  const int tid = threadIdx.x;
  const int m0 = blockIdx.x * 64;
  const int n0 = blockIdx.y * 64;
  const int reg = n0 >> 8;  // 0: W1, 1: W2, 2: Wa
  const int ty = tid >> 4, tx = tid & 15;
  float acc[4][4] = {};

  for (int kk = 0; kk < 128; kk += 32) {
    #pragma unroll
    for (int j = 0; j < 2; ++j) {
      int c = tid + j * 256;       // 0..511 float4 chunks (64 rows x 8 k-chunks)
      int rown = c >> 3, kc = c & 7;
      int gm = m0 + rown;
      float4 av = make_float4(0.f, 0.f, 0.f, 0.f);
      if (gm < NUM_REL) av = *(const float4*)(emb + (size_t)gm * DIM_IN + kk + kc * 4);
      As[kc * 4 + 0][rown] = av.x; As[kc * 4 + 1][rown] = av.y;
      As[kc * 4 + 2][rown] = av.z; As[kc * 4 + 3][rown] = av.w;
      int o = n0 + rown;
      float4 bv;
      if (reg == 0)      bv = *(const float4*)(attn_w + (size_t)o * 256 + kk + kc * 4);
      else if (reg == 1) bv = *(const float4*)(attn_w + (size_t)(o - 256) * 256 + 128 + kk + kc * 4);
      else               bv = *(const float4*)(aggr_w + (size_t)(o - 512) * 128 + kk + kc * 4);
      Bs[kc * 4 + 0][rown] = bv.x; Bs[kc * 4 + 1][rown] = bv.y;
      Bs[kc * 4 + 2][rown] = bv.z; Bs[kc * 4 + 3][rown] = bv.w;
    }
    __syncthreads();
    #pragma unroll
    for (int k = 0; k < 32; ++k) {
      float4 a4 = *(const float4*)&As[k][ty * 4];
      float4 b4 = *(const float4*)&Bs[k][tx * 4];
      float am[4] = {a4.x, a4.y, a4.z, a4.w};
      float bn[4] = {b4.x, b4.y, b4.z, b4.w};
      #pragma unroll
      for (int i = 0; i < 4; ++i)
        #pragma unroll
        for (int jj = 0; jj < 4; ++jj)
          acc[i][jj] += am[i] * bn[jj];
    }
    __syncthreads();
  }

  float bias[4];
  #pragma unroll
  for (int jj = 0; jj < 4; ++jj) {
    int gn = n0 + tx * 4 + jj;
    float b = 0.f;
    if (gn >= 512)      b = aggr_b[gn - 512];
    else if (gn >= 256) b = attn_b[gn - 256];
    bias[jj] = b;
  }
  #pragma unroll
  for (int i = 0; i < 4; ++i) {
    int gm = m0 + ty * 4 + i;
    if (gm >= NUM_REL) continue;
    float4 v;
    v.x = acc[i][0] + bias[0];
    v.y = acc[i][1] + bias[1];
    v.z = acc[i][2] + bias[2];
    v.w = acc[i][3] + bias[3];
    if (reg == 0) {
      *(float4*)(Pz + (size_t)gm * 256 + n0 + tx * 4) = v;
    } else {
      int col = (reg == 1) ? (n0 - 256) : (n0 - 512 + 256);
      __half2 h0 = __floats2half2_rn(v.x, v.y);
      __half2 h1 = __floats2half2_rn(v.z, v.w);
      uint2 u;
      u.x = *(unsigned*)&h0;
      u.y = *(unsigned*)&h1;
      *(uint2*)(Ph + (size_t)gm * 512 + col + tx * 4) = u;
    }
  }
}

// ---------------------------------------------------------------------------
// Histogram of edges per head relation.
// ---------------------------------------------------------------------------
__global__ __launch_bounds__(256) void hist_kernel(
    const int* __restrict__ trip, int* __restrict__ count) {
  int e = blockIdx.x * 256 + threadIdx.x;
  if (e < NUM_EDGES) atomicAdd(&count[trip[e * 3]], 1);
}

// ---------------------------------------------------------------------------
// Exclusive scan of per-relation counts -> CSR offsets (+ cursor copy).
// ---------------------------------------------------------------------------
__global__ __launch_bounds__(1024) void scan_kernel(
    const int* __restrict__ count, int* __restrict__ offs, int* __restrict__ cursor) {
  __shared__ int s[1024];
  const int t = threadIdx.x;
  const int base = t * 20;
  int loc[20];
  int sum = 0;
  #pragma unroll
  for (int i = 0; i < 20; ++i) {
    int idx = base + i;
    int v = (idx < NUM_REL) ? count[idx] : 0;
    loc[i] = sum;
    sum += v;
  }
  s[t] = sum;
  __syncthreads();
  for (int off = 1; off < 1024; off <<= 1) {
    int v = 0;
    if (t >= off) v = s[t - off];
    __syncthreads();
    if (t >= off) s[t] += v;
    __syncthreads();
  }
  int prev = (t > 0) ? s[t - 1] : 0;
  #pragma unroll
  for (int i = 0; i < 20; ++i) {
    int idx = base + i;
    if (idx < NUM_REL) {
      int o = prev + loc[i];
      offs[idx] = o;
      cursor[idx] = o;
    }
  }
  if (t == 1023) offs[NUM_REL] = s[1023];
}

// ---------------------------------------------------------------------------
// Bucket fill: tbsorted[pos] = tail | (bin << 15), grouped by head relation.
// ---------------------------------------------------------------------------
__global__ __launch_bounds__(256) void fill_kernel(
    const int* __restrict__ trip, int* __restrict__ cursor, int* __restrict__ tbsorted) {
  int e = blockIdx.x * 256 + threadIdx.x;
  if (e < NUM_EDGES) {
    int hd = trip[e * 3 + 0];
    int tl = trip[e * 3 + 1];
    int bn = trip[e * 3 + 2];
    int pos = atomicAdd(&cursor[hd], 1);
    tbsorted[pos] = tl | (bn << 15);
  }
}

// ---------------------------------------------------------------------------
// Fused per-relation: logits (fp16 ZT gather, pipelined) -> in-LDS softmax ->
// weighted fp16 MSG gather (wave-per-edge, 8B/lane, x2 unrolled).
// Block = 256 threads = one relation.
// ---------------------------------------------------------------------------
__global__ __launch_bounds__(256) void edge_agg_kernel(
    const float* __restrict__ Pz, const __half* __restrict__ Ph,
    const int* __restrict__ tbsorted, const int* __restrict__ offs,
    const float* __restrict__ attn_bin, const float* __restrict__ attn_vec,
    float* __restrict__ rawG, float* __restrict__ out) {
  const int r = blockIdx.x;
  const int tid = threadIdx.x;
  const int beg = offs[r];
  const int n = offs[r + 1] - beg;
  if (n == 0) {
    out[(size_t)r * 256 + tid] = 0.f;
    return;
  }
  __shared__ float rawS[RAWCAP][8];  // raw logits, later softmax weights
  __shared__ int tS[RAWCAP];
  __shared__ float red[32][8];
  __shared__ float redS[4][256];
  __shared__ float amaxS[8], invS[8];
  const int lane = tid & 63;
  const int w = tid >> 6;

  // ---- phase A: attention logits (tails 2 ahead, ZT row 1 ahead) ----
  {
    const float4 vv = *(const float4*)(attn_vec + lane * 4);
    const float4 zh = *(const float4*)(Pz + (size_t)r * 256 + lane * 4);
    int tb0 = (w < n) ? tbsorted[beg + w] : 0;
    int tb1 = (w + 4 < n) ? tbsorted[beg + w + 4] : 0;
    uint2 zt0 = make_uint2(0u, 0u);
    if (w < n) zt0 = *(const uint2*)(Ph + (size_t)(tb0 & 0x7fff) * 512 + lane * 4);
    for (int i = w; i < n; i += 4) {
      int tb2 = (i + 8 < n) ? tbsorted[beg + i + 8] : 0;
      uint2 zt1 = zt0;
      if (i + 4 < n) zt1 = *(const uint2*)(Ph + (size_t)(tb1 & 0x7fff) * 512 + lane * 4);
      int tl = tb0 & 0x7fff;
      int bn = tb0 >> 15;
      if (lane == 0 && i < RAWCAP) tS[i] = tl;
      float2 f0 = __half22float2(*(const __half2*)&zt0.x);
      float2 f1 = __half22float2(*(const __half2*)&zt0.y);
      float zx = zh.x + f0.x, zy = zh.y + f0.y, zz = zh.z + f1.x, zw = zh.w + f1.y;
      zx = zx > 0.f ? zx : 0.2f * zx;
      zy = zy > 0.f ? zy : 0.2f * zy;
      zz = zz > 0.f ? zz : 0.2f * zz;
      zw = zw > 0.f ? zw : 0.2f * zw;
      float p = zx * vv.x + zy * vv.y + zz * vv.z + zw * vv.w;
      p += __shfl_xor(p, 1);
      p += __shfl_xor(p, 2);
      p += __shfl_xor(p, 4);  // lanes 8h hold head-h dot
      if ((lane & 7) == 0) {
        int h = lane >> 3;
        float val = p + attn_bin[bn * 8 + h];
        if (i < RAWCAP) rawS[i][h] = val;
        else            rawG[(size_t)(beg + i) * 8 + h] = val;
      }
      tb0 = tb1; tb1 = tb2; zt0 = zt1;
    }
  }
  __syncthreads();

  // ---- softmax stats ----
  const int s_ = tid >> 3, h = tid & 7;
  float mx = -3.4e38f;
  for (int i = s_; i < n; i += 32)
    mx = fmaxf(mx, (i < RAWCAP) ? rawS[i][h] : rawG[(size_t)(beg + i) * 8 + h]);
  red[s_][h] = mx;
  __syncthreads();
  #pragma unroll
  for (int st = 16; st >= 1; st >>= 1) {
    if (s_ < st) red[s_][h] = fmaxf(red[s_][h], red[s_ + st][h]);
    __syncthreads();
  }
  if (tid < 8) amaxS[tid] = red[0][tid];
  __syncthreads();
  const float am = amaxS[h];
  float sm = 0.f;
  for (int i = s_; i < n; i += 32)
    sm += expf(((i < RAWCAP) ? rawS[i][h] : rawG[(size_t)(beg + i) * 8 + h]) - am);
  red[s_][h] = sm;
  __syncthreads();
  #pragma unroll
  for (int st = 16; st >= 1; st >>= 1) {
    if (s_ < st) red[s_][h] += red[s_ + st][h];
    __syncthreads();
  }
  if (tid < 8) invS[tid] = 1.f / (red[0][tid] + 1e-16f);
  __syncthreads();

  // convert LDS raw -> softmax weight in place
  const int nc = (n < RAWCAP) ? n : RAWCAP;
  for (int idx = tid; idx < nc * 8; idx += 256) {
    int i = idx >> 3, hh = idx & 7;
    rawS[i][hh] = expf(rawS[i][hh] - amaxS[hh]) * invS[hh];
  }
  __syncthreads();

  // ---- phase B: weighted MSG gather, wave-per-edge, 8B/lane fp16, x2 unroll ----
  {
    const int hB = lane >> 3;
    const __half* __restrict__ Pm = Ph + 256 + lane * 4;
    float4 a0 = make_float4(0.f, 0.f, 0.f, 0.f);
    float4 a1 = make_float4(0.f, 0.f, 0.f, 0.f);
    int i = w;
    for (; i + 4 < nc; i += 8) {
      int t0 = tS[i], t1 = tS[i + 4];
      float w0 = rawS[i][hB], w1 = rawS[i + 4][hB];
      uint2 u0 = *(const uint2*)(Pm + (size_t)t0 * 512);
      uint2 u1 = *(const uint2*)(Pm + (size_t)t1 * 512);
      float2 m00 = __half22float2(*(const __half2*)&u0.x);
      float2 m01 = __half22float2(*(const __half2*)&u0.y);
      float2 m10 = __half22float2(*(const __half2*)&u1.x);
      float2 m11 = __half22float2(*(const __half2*)&u1.y);
      a0.x += w0 * m00.x; a0.y += w0 * m00.y; a0.z += w0 * m01.x; a0.w += w0 * m01.y;
      a1.x += w1 * m10.x; a1.y += w1 * m10.y; a1.z += w1 * m11.x; a1.w += w1 * m11.y;
    }
    for (; i < nc; i += 4) {
      int t0 = tS[i];
      float w0 = rawS[i][hB];
      uint2 u0 = *(const uint2*)(Pm + (size_t)t0 * 512);
      float2 m00 = __half22float2(*(const __half2*)&u0.x);
      float2 m01 = __half22float2(*(const __half2*)&u0.y);
      a0.x += w0 * m00.x; a0.y += w0 * m00.y; a0.z += w0 * m01.x; a0.w += w0 * m01.y;
    }
    for (; i < n; i += 4) {  // rare fallback (n > RAWCAP)
      int tb = tbsorted[beg + i];
      int t0 = tb & 0x7fff;
      float w0 = expf(rawG[(size_t)(beg + i) * 8 + hB] - amaxS[hB]) * invS[hB];
      uint2 u0 = *(const uint2*)(Pm + (size_t)t0 * 512);
      float2 m00 = __half22float2(*(const __half2*)&u0.x);
      float2 m01 = __half22float2(*(const __half2*)&u0.y);
      a0.x += w0 * m00.x; a0.y += w0 * m00.y; a0.z += w0 * m01.x; a0.w += w0 * m01.y;
    }
    a0.x += a1.x; a0.y += a1.y; a0.z += a1.z; a0.w += a1.w;
    *(float4*)&redS[w][lane * 4] = a0;
  }
  __syncthreads();
  out[(size_t)r * 256 + tid] = redS[0][tid] + redS[1][tid] + redS[2][tid] + redS[3][tid];
}

extern "C" void kernel_launch(void* const* d_in, const int* in_sizes, int n_in,
                              void* d_out, int out_size, void* d_ws, size_t ws_size,
                              hipStream_t stream) {
  const float* emb      = (const float*)d_in[0];
  const int*   trip     = (const int*)d_in[1];
  const float* attn_w   = (const float*)d_in[2];
  const float* attn_b   = (const float*)d_in[3];
  const float* attn_bin = (const float*)d_in[4];
  const float* attn_vec = (const float*)d_in[5];
  const float* aggr_w   = (const float*)d_in[6];
  const float* aggr_b   = (const float*)d_in[7];
  float* out = (float*)d_out;

  // workspace layout (~64 MB)
  float* Pz     = (float*)d_ws;                           // 20000*256 f32  (ZH)
  __half* Ph    = (__half*)(Pz + (size_t)NUM_REL * 256);  // 20000*512 f16  (ZT|MSG)
  float* rawG   = (float*)(Ph + (size_t)NUM_REL * 512);   // 640000*8 f32 (fallback only)
  int* tbsorted = (int*)(rawG + (size_t)NUM_EDGES * 8);   // 640000 i32 (tail | bin<<15)
  int* count    = tbsorted + NUM_EDGES;                   // 20000 i32
  int* offs     = count + NUM_REL;                        // 20001 i32
  int* cursor   = offs + NUM_REL + 1;                     // 20000 i32

  hipMemsetAsync(count, 0, NUM_REL * sizeof(int), stream);

  dim3 ggrid((NUM_REL + 63) / 64, 768 / 64);
  hipLaunchKernelGGL(gemm_kernel, ggrid, dim3(256), 0, stream,
                     emb, attn_w, attn_b, aggr_w, aggr_b, Pz, Ph);
  hipLaunchKernelGGL(hist_kernel, dim3((NUM_EDGES + 255) / 256), dim3(256), 0, stream,
                     trip, count);
  hipLaunchKernelGGL(scan_kernel, dim3(1), dim3(1024), 0, stream,
                     count, offs, cursor);
  hipLaunchKernelGGL(fill_kernel, dim3((NUM_EDGES + 255) / 256), dim3(256), 0, stream,
                     trip, cursor, tbsorted);
  hipLaunchKernelGGL(edge_agg_kernel, dim3(NUM_REL), dim3(256), 0, stream,
                     Pz, Ph, tbsorted, offs, attn_bin, attn_vec, rawG, out);
}

// Round 7
// 314.419 us; speedup vs baseline: 1.8814x; 1.0736x over previous
//
#include <hip/hip_runtime.h>
#include <hip/hip_fp16.h>
#include <cstdint>
#include <cstddef>

#define NUM_REL 20000
#define NUM_EDGES 640000
#define DIM_IN 128
#define DIM_OUT 256
#define NUM_HEAD 8
#define DIM_HID 32
#define NUM_BIN 10
#define RAWCAP 128  // per-relation LDS capacity (max degree ~65 here; global fallback beyond)

// P16 row (768 halves): [0,256)=ZH, [256,512)=ZT(+attn_b), [512,768)=MSG(+aggr_b)

typedef _Float16 f16x8 __attribute__((ext_vector_type(8)));
typedef _Float16 h2 __attribute__((ext_vector_type(2)));
typedef float f32x4 __attribute__((ext_vector_type(4)));

union H2U { unsigned u; h2 h; };

// ---------------------------------------------------------------------------
// Convert combined weight matrix to fp16: Bh[o][k], o in [0,768), k in [0,128).
// o<256: W1 (attn_w[o][k]); o<512: W2 (attn_w[o-256][128+k]); else Wa.
// ---------------------------------------------------------------------------
__global__ __launch_bounds__(256) void convb_kernel(
    const float* __restrict__ attn_w, const float* __restrict__ aggr_w,
    __half* __restrict__ Bh) {
  int i = blockIdx.x * 256 + threadIdx.x;  // one float4 (4 elems) per thread
  if (i >= 768 * 128 / 4) return;
  int o = (i * 4) >> 7;
  int k = (i * 4) & 127;
  float4 v;
  if (o < 256)      v = *(const float4*)(attn_w + (size_t)o * 256 + k);
  else if (o < 512) v = *(const float4*)(attn_w + (size_t)(o - 256) * 256 + 128 + k);
  else              v = *(const float4*)(aggr_w + (size_t)(o - 512) * 128 + k);
  __half2 h0 = __floats2half2_rn(v.x, v.y);
  __half2 h1 = __floats2half2_rn(v.z, v.w);
  uint2 u;
  u.x = *(unsigned*)&h0;
  u.y = *(unsigned*)&h1;
  *(uint2*)(Bh + (size_t)o * 128 + k) = u;
}

// ---------------------------------------------------------------------------
// MFMA GEMM: P16[r][0..768) = emb[r] @ [W1|W2|Wa]^T (+bias on ZT/MSG), fp16 out.
// Block = 256 thr (4 waves) = 32 rows x 768 cols. Wave w: cols [w*192, w*192+192).
// mfma_f32_16x16x32_f16; A frag: row=lane&15, k=(lane>>4)*8+j (inline f32->f16);
// B frag symmetric from Bh (o-major = B^T, contiguous 16B); C: row=(lane>>4)*4+reg,
// col=lane&15.
// ---------------------------------------------------------------------------
__global__ __launch_bounds__(256) void gemm_mfma_kernel(
    const float* __restrict__ emb, const __half* __restrict__ Bh,
    const float* __restrict__ attn_b, const float* __restrict__ aggr_b,
    __half* __restrict__ P16) {
  const int tid = threadIdx.x;
  const int w = tid >> 6, l = tid & 63;
  const int m0 = blockIdx.x * 32;
  const int lr = l & 15, lk = l >> 4;

  // A fragments: a[rt][kt] covers rows m0+rt*16+lr, k = kt*32 + lk*8 + j
  f16x8 a[2][4];
  #pragma unroll
  for (int rt = 0; rt < 2; ++rt) {
    const float* src = emb + (size_t)(m0 + rt * 16 + lr) * 128 + lk * 8;
    #pragma unroll
    for (int kt = 0; kt < 4; ++kt) {
      float4 f0 = *(const float4*)(src + kt * 32);
      float4 f1 = *(const float4*)(src + kt * 32 + 4);
      f16x8 v;
      v[0] = (_Float16)f0.x; v[1] = (_Float16)f0.y; v[2] = (_Float16)f0.z; v[3] = (_Float16)f0.w;
      v[4] = (_Float16)f1.x; v[5] = (_Float16)f1.y; v[6] = (_Float16)f1.z; v[7] = (_Float16)f1.w;
      a[rt][kt] = v;
    }
  }

  #pragma unroll 1
  for (int ct = 0; ct < 12; ++ct) {
    const int col = w * 192 + ct * 16 + lr;
    f16x8 b[4];
    const __half* bsrc = Bh + (size_t)col * 128 + lk * 8;
    #pragma unroll
    for (int kt = 0; kt < 4; ++kt)
      b[kt] = *reinterpret_cast<const f16x8*>(bsrc + kt * 32);
    f32x4 acc0 = {0.f, 0.f, 0.f, 0.f};
    f32x4 acc1 = {0.f, 0.f, 0.f, 0.f};
    #pragma unroll
    for (int kt = 0; kt < 4; ++kt) {
      acc0 = __builtin_amdgcn_mfma_f32_16x16x32_f16(a[0][kt], b[kt], acc0, 0, 0, 0);
      acc1 = __builtin_amdgcn_mfma_f32_16x16x32_f16(a[1][kt], b[kt], acc1, 0, 0, 0);
    }
    float bias = 0.f;
    if (col >= 512)      bias = aggr_b[col - 512];
    else if (col >= 256) bias = attn_b[col - 256];
    #pragma unroll
    for (int r = 0; r < 4; ++r) {
      int row = m0 + lk * 4 + r;
      P16[(size_t)row * 768 + col]        = (__half)(acc0[r] + bias);
      P16[(size_t)(row + 16) * 768 + col] = (__half)(acc1[r] + bias);
    }
  }
}

// ---------------------------------------------------------------------------
// Histogram of edges per head relation.
// ---------------------------------------------------------------------------
__global__ __launch_bounds__(256) void hist_kernel(
    const int* __restrict__ trip, int* __restrict__ count) {
  int e = blockIdx.x * 256 + threadIdx.x;
  if (e < NUM_EDGES) atomicAdd(&count[trip[e * 3]], 1);
}

// ---------------------------------------------------------------------------
// Exclusive scan of per-relation counts -> CSR offsets (+ cursor copy).
// ---------------------------------------------------------------------------
__global__ __launch_bounds__(1024) void scan_kernel(
    const int* __restrict__ count, int* __restrict__ offs, int* __restrict__ cursor) {
  __shared__ int s[1024];
  const int t = threadIdx.x;
  const int base = t * 20;
  int loc[20];
  int sum = 0;
  #pragma unroll
  for (int i = 0; i < 20; ++i) {
    int idx = base + i;
    int v = (idx < NUM_REL) ? count[idx] : 0;
    loc[i] = sum;
    sum += v;
  }
  s[t] = sum;
  __syncthreads();
  for (int off = 1; off < 1024; off <<= 1) {
    int v = 0;
    if (t >= off) v = s[t - off];
    __syncthreads();
    if (t >= off) s[t] += v;
    __syncthreads();
  }
  int prev = (t > 0) ? s[t - 1] : 0;
  #pragma unroll
  for (int i = 0; i < 20; ++i) {
    int idx = base + i;
    if (idx < NUM_REL) {
      int o = prev + loc[i];
      offs[idx] = o;
      cursor[idx] = o;
    }
  }
  if (t == 1023) offs[NUM_REL] = s[1023];
}

// ---------------------------------------------------------------------------
// Bucket fill: tbsorted[pos] = tail | (bin << 15), grouped by head relation.
// ---------------------------------------------------------------------------
__global__ __launch_bounds__(256) void fill_kernel(
    const int* __restrict__ trip, int* __restrict__ cursor, int* __restrict__ tbsorted) {
  int e = blockIdx.x * 256 + threadIdx.x;
  if (e < NUM_EDGES) {
    int hd = trip[e * 3 + 0];
    int tl = trip[e * 3 + 1];
    int bn = trip[e * 3 + 2];
    int pos = atomicAdd(&cursor[hd], 1);
    tbsorted[pos] = tl | (bn << 15);
  }
}

// ---------------------------------------------------------------------------
// Fused per-relation: logits (fp16 pk-math: pk_add + leaky(0.6x+0.4|x|) +
// fdot2) -> in-LDS softmax -> weighted fp16 MSG gather.
// Block = 256 threads = one relation.
// ---------------------------------------------------------------------------
__global__ __launch_bounds__(256) void edge_agg_kernel(
    const __half* __restrict__ P16, const int* __restrict__ tbsorted,
    const int* __restrict__ offs, const float* __restrict__ attn_bin,
    const float* __restrict__ attn_vec, float* __restrict__ rawG,
    float* __restrict__ out) {
  const int r = blockIdx.x;
  const int tid = threadIdx.x;
  const int beg = offs[r];
  const int n = offs[r + 1] - beg;
  if (n == 0) {
    out[(size_t)r * 256 + tid] = 0.f;
    return;
  }
  __shared__ float rawS[RAWCAP][8];  // raw logits, later softmax weights
  __shared__ int tS[RAWCAP];
  __shared__ float red[32][8];
  __shared__ float redS[4][256];
  __shared__ float amaxS[8], invS[8];
  const int lane = tid & 63;
  const int w = tid >> 6;

  // ---- phase A: attention logits (tails 2 ahead, ZT row 1 ahead) ----
  {
    float4 vvf = *(const float4*)(attn_vec + lane * 4);
    h2 vv0 = {(_Float16)vvf.x, (_Float16)vvf.y};
    h2 vv1 = {(_Float16)vvf.z, (_Float16)vvf.w};
    const uint2 zhu = *(const uint2*)(P16 + (size_t)r * 768 + lane * 4);
    H2U zh0, zh1; zh0.u = zhu.x; zh1.u = zhu.y;
    const h2 c06 = {(_Float16)0.6f, (_Float16)0.6f};
    const h2 c04 = {(_Float16)0.4f, (_Float16)0.4f};

    int tb0 = (w < n) ? tbsorted[beg + w] : 0;
    int tb1 = (w + 4 < n) ? tbsorted[beg + w + 4] : 0;
    uint2 zt0 = make_uint2(0u, 0u);
    if (w < n) zt0 = *(const uint2*)(P16 + (size_t)(tb0 & 0x7fff) * 768 + 256 + lane * 4);
    for (int i = w; i < n; i += 4) {
      int tb2 = (i + 8 < n) ? tbsorted[beg + i + 8] : 0;
      uint2 zt1 = zt0;
      if (i + 4 < n) zt1 = *(const uint2*)(P16 + (size_t)(tb1 & 0x7fff) * 768 + 256 + lane * 4);
      int tl = tb0 & 0x7fff;
      int bn = tb0 >> 15;
      if (lane == 0 && i < RAWCAP) tS[i] = tl;
      H2U a0, a1; a0.u = zt0.x; a1.u = zt0.y;
      h2 z0 = zh0.h + a0.h;
      h2 z1 = zh1.h + a1.h;
      // leakyrelu(x, 0.2) = 0.6x + 0.4|x|
      H2U b0, b1; b0.h = z0; b1.h = z1;
      b0.u &= 0x7FFF7FFFu; b1.u &= 0x7FFF7FFFu;
      h2 l0 = z0 * c06 + b0.h * c04;
      h2 l1 = z1 * c06 + b1.h * c04;
      float p = __builtin_amdgcn_fdot2(l0, vv0, 0.f, false);
      p = __builtin_amdgcn_fdot2(l1, vv1, p, false);
      p += __shfl_xor(p, 1);
      p += __shfl_xor(p, 2);
      p += __shfl_xor(p, 4);  // lanes 8h hold head-h dot
      if ((lane & 7) == 0) {
        int h = lane >> 3;
        float val = p + attn_bin[bn * 8 + h];
        if (i < RAWCAP) rawS[i][h] = val;
        else            rawG[(size_t)(beg + i) * 8 + h] = val;
      }
      tb0 = tb1; tb1 = tb2; zt0 = zt1;
    }
  }
  __syncthreads();

  // ---- softmax stats ----
  const int s_ = tid >> 3, h = tid & 7;
  float mx = -3.4e38f;
  for (int i = s_; i < n; i += 32)
    mx = fmaxf(mx, (i < RAWCAP) ? rawS[i][h] : rawG[(size_t)(beg + i) * 8 + h]);
  red[s_][h] = mx;
  __syncthreads();
  #pragma unroll
  for (int st = 16; st >= 1; st >>= 1) {
    if (s_ < st) red[s_][h] = fmaxf(red[s_][h], red[s_ + st][h]);
    __syncthreads();
  }
  if (tid < 8) amaxS[tid] = red[0][tid];
  __syncthreads();
  const float am = amaxS[h];
  float sm = 0.f;
  for (int i = s_; i < n; i += 32)
    sm += expf(((i < RAWCAP) ? rawS[i][h] : rawG[(size_t)(beg + i) * 8 + h]) - am);
  red[s_][h] = sm;
  __syncthreads();
  #pragma unroll
  for (int st = 16; st >= 1; st >>= 1) {
    if (s_ < st) red[s_][h] += red[s_ + st][h];
    __syncthreads();
  }
  if (tid < 8) invS[tid] = 1.f / (red[0][tid] + 1e-16f);
  __syncthreads();

  // convert LDS raw -> softmax weight in place
  const int nc = (n < RAWCAP) ? n : RAWCAP;
  for (int idx = tid; idx < nc * 8; idx += 256) {
    int i = idx >> 3, hh = idx & 7;
    rawS[i][hh] = expf(rawS[i][hh] - amaxS[hh]) * invS[hh];
  }
  __syncthreads();

  // ---- phase B: weighted MSG gather, wave-per-edge, 8B/lane fp16, x2 unroll ----
  {
    const int hB = lane >> 3;
    const __half* __restrict__ Pm = P16 + 512 + lane * 4;
    float4 a0 = make_float4(0.f, 0.f, 0.f, 0.f);
    float4 a1 = make_float4(0.f, 0.f, 0.f, 0.f);
    int i = w;
    for (; i + 4 < nc; i += 8) {
      int t0 = tS[i], t1 = tS[i + 4];
      float w0 = rawS[i][hB], w1 = rawS[i + 4][hB];
      uint2 u0 = *(const uint2*)(Pm + (size_t)t0 * 768);
      uint2 u1 = *(const uint2*)(Pm + (size_t)t1 * 768);
      float2 m00 = __half22float2(*(const __half2*)&u0.x);
      float2 m01 = __half22float2(*(const __half2*)&u0.y);
      float2 m10 = __half22float2(*(const __half2*)&u1.x);
      float2 m11 = __half22float2(*(const __half2*)&u1.y);
      a0.x += w0 * m00.x; a0.y += w0 * m00.y; a0.z += w0 * m01.x; a0.w += w0 * m01.y;
      a1.x += w1 * m10.x; a1.y += w1 * m10.y; a1.z += w1 * m11.x; a1.w += w1 * m11.y;
    }
    for (; i < nc; i += 4) {
      int t0 = tS[i];
      float w0 = rawS[i][hB];
      uint2 u0 = *(const uint2*)(Pm + (size_t)t0 * 768);
      float2 m00 = __half22float2(*(const __half2*)&u0.x);
      float2 m01 = __half22float2(*(const __half2*)&u0.y);
      a0.x += w0 * m00.x; a0.y += w0 * m00.y; a0.z += w0 * m01.x; a0.w += w0 * m01.y;
    }
    for (; i < n; i += 4) {  // rare fallback (n > RAWCAP)
      int tb = tbsorted[beg + i];
      int t0 = tb & 0x7fff;
      float w0 = expf(rawG[(size_t)(beg + i) * 8 + hB] - amaxS[hB]) * invS[hB];
      uint2 u0 = *(const uint2*)(Pm + (size_t)t0 * 768);
      float2 m00 = __half22float2(*(const __half2*)&u0.x);
      float2 m01 = __half22float2(*(const __half2*)&u0.y);
      a0.x += w0 * m00.x; a0.y += w0 * m00.y; a0.z += w0 * m01.x; a0.w += w0 * m01.y;
    }
    a0.x += a1.x; a0.y += a1.y; a0.z += a1.z; a0.w += a1.w;
    *(float4*)&redS[w][lane * 4] = a0;
  }
  __syncthreads();
  out[(size_t)r * 256 + tid] = redS[0][tid] + redS[1][tid] + redS[2][tid] + redS[3][tid];
}

extern "C" void kernel_launch(void* const* d_in, const int* in_sizes, int n_in,
                              void* d_out, int out_size, void* d_ws, size_t ws_size,
                              hipStream_t stream) {
  const float* emb      = (const float*)d_in[0];
  const int*   trip     = (const int*)d_in[1];
  const float* attn_w   = (const float*)d_in[2];
  const float* attn_b   = (const float*)d_in[3];
  const float* attn_bin = (const float*)d_in[4];
  const float* attn_vec = (const float*)d_in[5];
  const float* aggr_w   = (const float*)d_in[6];
  const float* aggr_b   = (const float*)d_in[7];
  float* out = (float*)d_out;

  // workspace layout (~54 MB)
  __half* P16   = (__half*)d_ws;                          // 20000*768 f16
  __half* Bh    = P16 + (size_t)NUM_REL * 768;            // 768*128 f16
  float* rawG   = (float*)(Bh + 768 * 128);               // 640000*8 f32 (fallback only)
  int* tbsorted = (int*)(rawG + (size_t)NUM_EDGES * 8);   // 640000 i32 (tail | bin<<15)
  int* count    = tbsorted + NUM_EDGES;                   // 20000 i32
  int* offs     = count + NUM_REL;                        // 20001 i32
  int* cursor   = offs + NUM_REL + 1;                     // 20000 i32

  hipMemsetAsync(count, 0, NUM_REL * sizeof(int), stream);

  hipLaunchKernelGGL(convb_kernel, dim3((768 * 128 / 4 + 255) / 256), dim3(256), 0, stream,
                     attn_w, aggr_w, Bh);
  hipLaunchKernelGGL(gemm_mfma_kernel, dim3(NUM_REL / 32), dim3(256), 0, stream,
                     emb, Bh, attn_b, aggr_b, P16);
  hipLaunchKernelGGL(hist_kernel, dim3((NUM_EDGES + 255) / 256), dim3(256), 0, stream,
                     trip, count);
  hipLaunchKernelGGL(scan_kernel, dim3(1), dim3(1024), 0, stream,
                     count, offs, cursor);
  hipLaunchKernelGGL(fill_kernel, dim3((NUM_EDGES + 255) / 256), dim3(256), 0, stream,
                     trip, cursor, tbsorted);
  hipLaunchKernelGGL(edge_agg_kernel, dim3(NUM_REL), dim3(256), 0, stream,
                     P16, tbsorted, offs, attn_bin, attn_vec, rawG, out);
}

// Round 8
// 298.181 us; speedup vs baseline: 1.9839x; 1.0545x over previous
//
#include <hip/hip_runtime.h>
#include <hip/hip_fp16.h>
#include <cstdint>
#include <cstddef>

#define NUM_REL 20000
#define NUM_EDGES 640000
#define DIM_IN 128
#define DIM_OUT 256
#define NUM_HEAD 8
#define DIM_HID 32
#define NUM_BIN 10

// P16 row (768 halves): [0,256)=ZH, [256,512)=ZT(+attn_b), [512,768)=MSG(+aggr_b)

typedef _Float16 f16x8 __attribute__((ext_vector_type(8)));
typedef _Float16 h2 __attribute__((ext_vector_type(2)));
typedef float f32x4 __attribute__((ext_vector_type(4)));

union H2U { unsigned u; h2 h; };

// ---------------------------------------------------------------------------
// Convert combined weight matrix to fp16: Bh[o][k], o in [0,768), k in [0,128).
// ---------------------------------------------------------------------------
__global__ __launch_bounds__(256) void convb_kernel(
    const float* __restrict__ attn_w, const float* __restrict__ aggr_w,
    __half* __restrict__ Bh) {
  int i = blockIdx.x * 256 + threadIdx.x;  // one float4 (4 elems) per thread
  if (i >= 768 * 128 / 4) return;
  int o = (i * 4) >> 7;
  int k = (i * 4) & 127;
  float4 v;
  if (o < 256)      v = *(const float4*)(attn_w + (size_t)o * 256 + k);
  else if (o < 512) v = *(const float4*)(attn_w + (size_t)(o - 256) * 256 + 128 + k);
  else              v = *(const float4*)(aggr_w + (size_t)(o - 512) * 128 + k);
  __half2 h0 = __floats2half2_rn(v.x, v.y);
  __half2 h1 = __floats2half2_rn(v.z, v.w);
  uint2 u;
  u.x = *(unsigned*)&h0;
  u.y = *(unsigned*)&h1;
  *(uint2*)(Bh + (size_t)o * 128 + k) = u;
}

// ---------------------------------------------------------------------------
// MFMA GEMM: P16[r][0..768) = emb[r] @ [W1|W2|Wa]^T (+bias on ZT/MSG), fp16 out.
// Block = 256 thr (4 waves) = 32 rows x 768 cols. Wave w: cols [w*192, w*192+192).
// ---------------------------------------------------------------------------
__global__ __launch_bounds__(256) void gemm_mfma_kernel(
    const float* __restrict__ emb, const __half* __restrict__ Bh,
    const float* __restrict__ attn_b, const float* __restrict__ aggr_b,
    __half* __restrict__ P16) {
  const int tid = threadIdx.x;
  const int w = tid >> 6, l = tid & 63;
  const int m0 = blockIdx.x * 32;
  const int lr = l & 15, lk = l >> 4;

  // A fragments: a[rt][kt] covers rows m0+rt*16+lr, k = kt*32 + lk*8 + j
  f16x8 a[2][4];
  #pragma unroll
  for (int rt = 0; rt < 2; ++rt) {
    const float* src = emb + (size_t)(m0 + rt * 16 + lr) * 128 + lk * 8;
    #pragma unroll
    for (int kt = 0; kt < 4; ++kt) {
      float4 f0 = *(const float4*)(src + kt * 32);
      float4 f1 = *(const float4*)(src + kt * 32 + 4);
      f16x8 v;
      v[0] = (_Float16)f0.x; v[1] = (_Float16)f0.y; v[2] = (_Float16)f0.z; v[3] = (_Float16)f0.w;
      v[4] = (_Float16)f1.x; v[5] = (_Float16)f1.y; v[6] = (_Float16)f1.z; v[7] = (_Float16)f1.w;
      a[rt][kt] = v;
    }
  }

  #pragma unroll 1
  for (int ct = 0; ct < 12; ++ct) {
    const int col = w * 192 + ct * 16 + lr;
    f16x8 b[4];
    const __half* bsrc = Bh + (size_t)col * 128 + lk * 8;
    #pragma unroll
    for (int kt = 0; kt < 4; ++kt)
      b[kt] = *reinterpret_cast<const f16x8*>(bsrc + kt * 32);
    f32x4 acc0 = {0.f, 0.f, 0.f, 0.f};
    f32x4 acc1 = {0.f, 0.f, 0.f, 0.f};
    #pragma unroll
    for (int kt = 0; kt < 4; ++kt) {
      acc0 = __builtin_amdgcn_mfma_f32_16x16x32_f16(a[0][kt], b[kt], acc0, 0, 0, 0);
      acc1 = __builtin_amdgcn_mfma_f32_16x16x32_f16(a[1][kt], b[kt], acc1, 0, 0, 0);
    }
    float bias = 0.f;
    if (col >= 512)      bias = aggr_b[col - 512];
    else if (col >= 256) bias = attn_b[col - 256];
    #pragma unroll
    for (int r = 0; r < 4; ++r) {
      int row = m0 + lk * 4 + r;
      P16[(size_t)row * 768 + col]        = (__half)(acc0[r] + bias);
      P16[(size_t)(row + 16) * 768 + col] = (__half)(acc1[r] + bias);
    }
  }
}

// ---------------------------------------------------------------------------
// Histogram of edges per head relation.
// ---------------------------------------------------------------------------
__global__ __launch_bounds__(256) void hist_kernel(
    const int* __restrict__ trip, int* __restrict__ count) {
  int e = blockIdx.x * 256 + threadIdx.x;
  if (e < NUM_EDGES) atomicAdd(&count[trip[e * 3]], 1);
}

// ---------------------------------------------------------------------------
// Exclusive scan of per-relation counts -> CSR offsets (+ cursor copy).
// ---------------------------------------------------------------------------
__global__ __launch_bounds__(1024) void scan_kernel(
    const int* __restrict__ count, int* __restrict__ offs, int* __restrict__ cursor) {
  __shared__ int s[1024];
  const int t = threadIdx.x;
  const int base = t * 20;
  int loc[20];
  int sum = 0;
  #pragma unroll
  for (int i = 0; i < 20; ++i) {
    int idx = base + i;
    int v = (idx < NUM_REL) ? count[idx] : 0;
    loc[i] = sum;
    sum += v;
  }
  s[t] = sum;
  __syncthreads();
  for (int off = 1; off < 1024; off <<= 1) {
    int v = 0;
    if (t >= off) v = s[t - off];
    __syncthreads();
    if (t >= off) s[t] += v;
    __syncthreads();
  }
  int prev = (t > 0) ? s[t - 1] : 0;
  #pragma unroll
  for (int i = 0; i < 20; ++i) {
    int idx = base + i;
    if (idx < NUM_REL) {
      int o = prev + loc[i];
      offs[idx] = o;
      cursor[idx] = o;
    }
  }
  if (t == 1023) offs[NUM_REL] = s[1023];
}

// ---------------------------------------------------------------------------
// Bucket fill: tbsorted[pos] = tail | (bin << 15), grouped by head relation.
// ---------------------------------------------------------------------------
__global__ __launch_bounds__(256) void fill_kernel(
    const int* __restrict__ trip, int* __restrict__ cursor, int* __restrict__ tbsorted) {
  int e = blockIdx.x * 256 + threadIdx.x;
  if (e < NUM_EDGES) {
    int hd = trip[e * 3 + 0];
    int tl = trip[e * 3 + 1];
    int bn = trip[e * 3 + 2];
    int pos = atomicAdd(&cursor[hd], 1);
    tbsorted[pos] = tl | (bn << 15);
  }
}

// ---------------------------------------------------------------------------
// Single-pass fused edge kernel (online softmax): per edge, gather ZT+MSG of
// the tail row once; logit via packed-fp16 math; per-head running (m, s) with
// rescaled accumulation; 4-wave merge in LDS epilogue.
// Block = 256 threads = one head relation. Lane l owns z/msg components
// 4l..4l+3 (head h = l>>3); butterfly shfl leaves the head-dot in ALL lanes
// of the 8-lane group, so the online update is fully lane-parallel.
// ---------------------------------------------------------------------------
__global__ __launch_bounds__(256) void edge_agg_kernel(
    const __half* __restrict__ P16, const int* __restrict__ tbsorted,
    const int* __restrict__ offs, const float* __restrict__ attn_bin,
    const float* __restrict__ attn_vec, float* __restrict__ out) {
  const int r = blockIdx.x;
  const int tid = threadIdx.x;
  const int beg = offs[r];
  const int n = offs[r + 1] - beg;
  if (n == 0) {
    out[(size_t)r * 256 + tid] = 0.f;
    return;
  }
  __shared__ float binS[NUM_BIN][8];
  __shared__ float mS[4][8], sS[4][8];
  __shared__ float accS[4][256];
  const int lane = tid & 63;
  const int w = tid >> 6;
  const int h = lane >> 3;

  if (tid < NUM_BIN * 8) binS[tid >> 3][tid & 7] = attn_bin[tid];
  __syncthreads();

  // per-lane online-softmax state (identical within each 8-lane head group)
  float m = -3.4e38f, s = 0.f;
  float4 acc = make_float4(0.f, 0.f, 0.f, 0.f);

  {
    float4 vvf = *(const float4*)(attn_vec + lane * 4);
    h2 vv0 = {(_Float16)vvf.x, (_Float16)vvf.y};
    h2 vv1 = {(_Float16)vvf.z, (_Float16)vvf.w};
    const uint2 zhu = *(const uint2*)(P16 + (size_t)r * 768 + lane * 4);
    H2U zh0, zh1; zh0.u = zhu.x; zh1.u = zhu.y;
    const h2 c06 = {(_Float16)0.6f, (_Float16)0.6f};
    const h2 c04 = {(_Float16)0.4f, (_Float16)0.4f};

    // pipeline: tails 2 ahead, tail row (ZT+MSG) 1 ahead
    int tb0 = (w < n) ? tbsorted[beg + w] : 0;
    int tb1 = (w + 4 < n) ? tbsorted[beg + w + 4] : 0;
    uint2 zt0 = make_uint2(0u, 0u), mg0 = make_uint2(0u, 0u);
    if (w < n) {
      const __half* row = P16 + (size_t)(tb0 & 0x7fff) * 768 + lane * 4;
      zt0 = *(const uint2*)(row + 256);
      mg0 = *(const uint2*)(row + 512);
    }
    for (int i = w; i < n; i += 4) {
      int tb2 = (i + 8 < n) ? tbsorted[beg + i + 8] : 0;
      uint2 zt1 = zt0, mg1 = mg0;
      if (i + 4 < n) {
        const __half* row = P16 + (size_t)(tb1 & 0x7fff) * 768 + lane * 4;
        zt1 = *(const uint2*)(row + 256);
        mg1 = *(const uint2*)(row + 512);
      }
      int bn = tb0 >> 15;
      // logit
      H2U a0, a1; a0.u = zt0.x; a1.u = zt0.y;
      h2 z0 = zh0.h + a0.h;
      h2 z1 = zh1.h + a1.h;
      H2U b0, b1; b0.h = z0; b1.h = z1;
      b0.u &= 0x7FFF7FFFu; b1.u &= 0x7FFF7FFFu;   // |x|
      h2 l0 = z0 * c06 + b0.h * c04;              // leakyrelu(x,0.2)=0.6x+0.4|x|
      h2 l1 = z1 * c06 + b1.h * c04;
      float p = __builtin_amdgcn_fdot2(l0, vv0, 0.f, false);
      p = __builtin_amdgcn_fdot2(l1, vv1, p, false);
      p += __shfl_xor(p, 1);
      p += __shfl_xor(p, 2);
      p += __shfl_xor(p, 4);  // every lane of the 8-group now holds the head dot
      float raw = p + binS[bn][h];
      // online-softmax update (branchless)
      float mn = fmaxf(m, raw);
      float sc = __expf(m - mn);
      float wv = __expf(raw - mn);
      s = s * sc + wv;
      m = mn;
      float2 g0 = __half22float2(*(const __half2*)&mg0.x);
      float2 g1 = __half22float2(*(const __half2*)&mg0.y);
      acc.x = acc.x * sc + wv * g0.x;
      acc.y = acc.y * sc + wv * g0.y;
      acc.z = acc.z * sc + wv * g1.x;
      acc.w = acc.w * sc + wv * g1.y;
      tb0 = tb1; tb1 = tb2; zt0 = zt1; mg0 = mg1;
    }
  }

  // ---- 4-wave merge ----
  if ((lane & 7) == 0) { mS[w][h] = m; sS[w][h] = s; }
  *(float4*)&accS[w][lane * 4] = acc;
  __syncthreads();

  const int h2_ = tid >> 5;  // output col = tid, head = tid>>5
  float M = fmaxf(fmaxf(mS[0][h2_], mS[1][h2_]), fmaxf(mS[2][h2_], mS[3][h2_]));
  float S = 0.f, o = 0.f;
  #pragma unroll
  for (int w4 = 0; w4 < 4; ++w4) {
    float e = __expf(mS[w4][h2_] - M);
    S += sS[w4][h2_] * e;
    o += accS[w4][tid] * e;
  }
  out[(size_t)r * 256 + tid] = o / (S + 1e-16f);
}

extern "C" void kernel_launch(void* const* d_in, const int* in_sizes, int n_in,
                              void* d_out, int out_size, void* d_ws, size_t ws_size,
                              hipStream_t stream) {
  const float* emb      = (const float*)d_in[0];
  const int*   trip     = (const int*)d_in[1];
  const float* attn_w   = (const float*)d_in[2];
  const float* attn_b   = (const float*)d_in[3];
  const float* attn_bin = (const float*)d_in[4];
  const float* attn_vec = (const float*)d_in[5];
  const float* aggr_w   = (const float*)d_in[6];
  const float* aggr_b   = (const float*)d_in[7];
  float* out = (float*)d_out;

  // workspace layout (~33 MB)
  __half* P16   = (__half*)d_ws;                          // 20000*768 f16
  __half* Bh    = P16 + (size_t)NUM_REL * 768;            // 768*128 f16
  int* tbsorted = (int*)(Bh + 768 * 128);                 // 640000 i32 (tail | bin<<15)
  int* count    = tbsorted + NUM_EDGES;                   // 20000 i32
  int* offs     = count + NUM_REL;                        // 20001 i32
  int* cursor   = offs + NUM_REL + 1;                     // 20000 i32

  hipMemsetAsync(count, 0, NUM_REL * sizeof(int), stream);

  hipLaunchKernelGGL(convb_kernel, dim3((768 * 128 / 4 + 255) / 256), dim3(256), 0, stream,
                     attn_w, aggr_w, Bh);
  hipLaunchKernelGGL(gemm_mfma_kernel, dim3(NUM_REL / 32), dim3(256), 0, stream,
                     emb, Bh, attn_b, aggr_b, P16);
  hipLaunchKernelGGL(hist_kernel, dim3((NUM_EDGES + 255) / 256), dim3(256), 0, stream,
                     trip, count);
  hipLaunchKernelGGL(scan_kernel, dim3(1), dim3(1024), 0, stream,
                     count, offs, cursor);
  hipLaunchKernelGGL(fill_kernel, dim3((NUM_EDGES + 255) / 256), dim3(256), 0, stream,
                     trip, cursor, tbsorted);
  hipLaunchKernelGGL(edge_agg_kernel, dim3(NUM_REL), dim3(256), 0, stream,
                     P16, tbsorted, offs, attn_bin, attn_vec, out);
}